// Round 3
// baseline (1315.338 us; speedup 1.0000x reference)
//
#include <hip/hip_runtime.h>
#include <hip/hip_bf16.h>

#define AA 64
#define NBRF 41
#define ORIGD 92
#define NATOM 50000
#define MM 12
#define NB 1000
#define NPCC 50
#define NEDGE (NATOM*MM)
#define NREP 64
constexpr float EPS_BN = 1e-5f;

using bf16 = __hip_bfloat16;
typedef short s16x8 __attribute__((ext_vector_type(8)));
typedef float f32x4 __attribute__((ext_vector_type(4)));

__device__ __forceinline__ float u2f(unsigned short u) {
    union { float f; unsigned int i; } v; v.i = ((unsigned int)u) << 16; return v.f;
}
__device__ __forceinline__ unsigned short f2bu(float f) {
    bf16 h = __float2bfloat16(f);
    return *reinterpret_cast<unsigned short*>(&h);
}
__device__ __forceinline__ float fsigmoid(float x) {
    float e = __expf(-x);
    return __builtin_amdgcn_rcpf(1.f + e);
}
__device__ __forceinline__ float fsoftplus(float x) {
    return fmaxf(x, 0.f) + __logf(1.f + __expf(-fabsf(x)));
}

// ---------------- zero small stats region ----------------
__global__ void k_zero(float* p, int n) {
    int i = blockIdx.x * blockDim.x + threadIdx.x;
    if (i < n) p[i] = 0.f;
}

// ---------------- prep: W2^T -> bf16 [128 rows(n)][72 (k, padded)] ----------------
__global__ void k_prepB(const float* __restrict__ W2, unsigned short* __restrict__ Bt) {
    for (int i = threadIdx.x; i < 128 * 72; i += 256) {
        int n = i / 72, kk = i - n * 72;
        float v = (kk < NBRF) ? W2[kk * 128 + n] : 0.f;
        Bt[i] = f2bu(v);
    }
}

// ---------------- prep: adj_w -> Bq bf16 [384 rows(n=o*64+e)][72 (k=d, padded)] ----------------
__global__ void k_prepQ(const float* __restrict__ adjw, unsigned short* __restrict__ Bq) {
    int i = blockIdx.x * 256 + threadIdx.x; // 384*72 = 27648
    if (i >= 384 * 72) return;
    int n = i / 72, k = i - n * 72;
    float v = (k < 64) ? adjw[(n >> 6) * 4096 + k * 64 + (n & 63)] : 0.f;
    Bq[i] = f2bu(v);
}

// ---------------- embed: x = atom_fea @ emb_w  (N,92)@(92,64) ----------------
__global__ __launch_bounds__(256) void k_embed(const float* __restrict__ af,
                                               const float* __restrict__ w,
                                               float* __restrict__ x) {
    __shared__ float wl[ORIGD * AA];
    __shared__ float al[4][ORIGD];
    int t = threadIdx.x;
    for (int i = t; i < ORIGD * AA; i += 256) wl[i] = w[i];
    int n0 = blockIdx.x * 4;
    for (int i = t; i < 4 * ORIGD; i += 256) {
        int a = i / ORIGD, k = i - a * ORIGD;
        al[a][k] = af[(size_t)(n0 + a) * ORIGD + k];
    }
    __syncthreads();
    int c = t & 63, a = t >> 6;
    float acc = 0.f;
    #pragma unroll 4
    for (int k = 0; k < ORIGD; ++k)
        acc += al[a][k] * wl[k * AA + c];
    x[(size_t)(n0 + a) * AA + c] = acc;
}

// ---------------- y0 = x@W[0:64], y1 = x@W[64:128] ----------------
__global__ __launch_bounds__(256) void k_y01(const float* __restrict__ x,
                                             const float* __restrict__ W, // 169x128 layer base
                                             float* __restrict__ y0, float* __restrict__ y1) {
    __shared__ float wl[64 * 128];
    __shared__ float xl[16][AA];
    int t = threadIdx.x;
    int n0 = blockIdx.x * 16;
    for (int i = t; i < 16 * AA; i += 256) {
        int a = i >> 6, k = i & 63;
        xl[a][k] = x[(size_t)(n0 + a) * AA + k];
    }
    int tc = t & 31, sub = t >> 5;
    int c0 = tc * 4;
    for (int half = 0; half < 2; ++half) {
        if (half) __syncthreads();
        const float* Wh = W + (size_t)half * 64 * 128;
        for (int i = t; i < 64 * 128; i += 256) wl[i] = Wh[i];
        __syncthreads();
        float* yout = half ? y1 : y0;
        for (int ah = 0; ah < 2; ++ah) {
            int a = sub + ah * 8;
            float a0=0,a1=0,a2=0,a3=0;
            #pragma unroll 8
            for (int k = 0; k < AA; ++k) {
                float xv = xl[a][k];
                float4 w4 = *reinterpret_cast<const float4*>(&wl[k * 128 + c0]);
                a0 += xv * w4.x; a1 += xv * w4.y; a2 += xv * w4.z; a3 += xv * w4.w;
            }
            float4 r = {a0,a1,a2,a3};
            *reinterpret_cast<float4*>(&yout[(size_t)(n0 + a) * 128 + c0]) = r;
        }
    }
}

// ================= MFMA edge-GEMM pass A =================
// Per block: 16 atoms -> 192 edges. [192 x 64pad] @ [64pad x 128] bf16.
// Computes BN1 stats AND stores gated r = z + y0 + y1 as bf16 (swizzled, coalesced).
// Epilogue v3 (T14 async-stage): per-thread il from global at kernel start;
// y0 + chunk-0 y1 rows gathered into REGISTERS during Al/Bl staging + MFMA,
// written to LDS late; chunk mt+1 gathers fly during compute of chunk mt.

#define MFMA_LOOP(acc, Al, Bl, w, ln, quad)                                         \
    _Pragma("unroll")                                                               \
    for (int mt = 0; mt < 3; ++mt) {                                                \
        int mrow = ((w) * 3 + mt) * 16 + (ln);                                      \
        s16x8 a0 = *reinterpret_cast<const s16x8*>(&(Al)[mrow * 72 + (quad) * 8]);  \
        s16x8 a1 = *reinterpret_cast<const s16x8*>(&(Al)[mrow * 72 + (quad) * 8 + 32]); \
        _Pragma("unroll")                                                           \
        for (int nt = 0; nt < 8; ++nt) {                                            \
            int nrow = nt * 16 + (ln);                                              \
            s16x8 b0 = *reinterpret_cast<const s16x8*>(&(Bl)[nrow * 72 + (quad) * 8]);      \
            s16x8 b1 = *reinterpret_cast<const s16x8*>(&(Bl)[nrow * 72 + (quad) * 8 + 32]); \
            acc[mt][nt] = __builtin_amdgcn_mfma_f32_16x16x32_bf16(a0, b0, acc[mt][nt], 0, 0, 0); \
            acc[mt][nt] = __builtin_amdgcn_mfma_f32_16x16x32_bf16(a1, b1, acc[mt][nt], 0, 0, 0); \
        }                                                                           \
    }

__global__ __launch_bounds__(256, 3) void k_passA(const float* __restrict__ y0,
                                                  const float* __restrict__ y1,
                                                  const float* __restrict__ nf,
                                                  const unsigned short* __restrict__ Bt,
                                                  const int* __restrict__ nidx,
                                                  float* __restrict__ stats,
                                                  uint4* __restrict__ gated) {
    // Al 192*72 (27648B) + Bl 128*72 (18432B) = 46080B, aliased in epilogue as
    // y1s[64][132] (33792B) + y0s[16][132] (8448B) = 42240B, then red[1024] f32.
    __shared__ __attribute__((aligned(16))) unsigned short AB[192 * 72 + 128 * 72];
    unsigned short* Al = AB;
    unsigned short* Bl = AB + 192 * 72;
    int t = threadIdx.x;
    int n0 = blockIdx.x * 16;
    int w = t >> 6, lane = t & 63, ln = lane & 15, quad = lane >> 4;
    int c4 = t & 31, rbase = t >> 5; // staging role: column-quad c4, rows rbase+8j

    // ---- prologue: issue index loads (broadcast within 32-thread groups) ----
    int mj[8];
    #pragma unroll
    for (int j = 0; j < 8; ++j) {
        int r = rbase + 8 * j;
        mj[j] = (r >> 4) * 48 + (r & 15); // chunk-0 edge row for stage row r
    }
    const int* nb = nidx + n0 * MM;
    int il0[8], il1[8];
    #pragma unroll
    for (int j = 0; j < 8; ++j) il0[j] = nb[mj[j]];
    #pragma unroll
    for (int j = 0; j < 8; ++j) il1[j] = nb[mj[j] + 16];

    // ---- stage Al (nbr_fea) / Bl (weights) while il loads are in flight ----
    {
        const float* fg = nf + (size_t)n0 * MM * NBRF;
        #pragma unroll 4
        for (int i = t; i < 192 * NBRF; i += 256) {
            int m = i / NBRF, k = i - m * NBRF;
            Al[m * 72 + k] = f2bu(fg[i]);
        }
        #pragma unroll
        for (int i = t; i < 192 * 23; i += 256) {
            int m = i / 23, k = 41 + (i - m * 23);
            Al[m * 72 + k] = 0;
        }
        #pragma unroll 4
        for (int i = t; i < 128 * 9; i += 256)
            reinterpret_cast<uint4*>(Bl)[i] = reinterpret_cast<const uint4*>(Bt)[i];
    }

    // ---- issue y0 + chunk-0 y1 gathers into registers (fly during MFMA) ----
    uint4 y0r0 = *reinterpret_cast<const uint4*>(&y0[(size_t)(n0 + rbase) * 128 + c4 * 4]);
    uint4 y0r1 = *reinterpret_cast<const uint4*>(&y0[(size_t)(n0 + rbase + 8) * 128 + c4 * 4]);
    uint4 R[8];
    #pragma unroll
    for (int j = 0; j < 8; ++j)
        R[j] = *reinterpret_cast<const uint4*>(&y1[(size_t)il0[j] * 128 + c4 * 4]);

    __syncthreads(); // Al/Bl ready

    f32x4 acc[3][8];
    f32x4 z4 = {0.f, 0.f, 0.f, 0.f};
    for (int i = 0; i < 3; ++i) for (int j = 0; j < 8; ++j) acc[i][j] = z4;
    MFMA_LOOP(acc, Al, Bl, w, ln, quad);

    int il2[8];
    #pragma unroll
    for (int j = 0; j < 8; ++j) il2[j] = nb[mj[j] + 32];

    __syncthreads(); // Al/Bl dead -> alias as staging buffers

    float* y1s = reinterpret_cast<float*>(AB);   // [64][132]
    float* y0s = y1s + 64 * 132;                 // [16][132]
    // write-late: y0 rows + chunk-0 y1 rows from registers
    *reinterpret_cast<uint4*>(&y0s[rbase * 132 + c4 * 4]) = y0r0;
    *reinterpret_cast<uint4*>(&y0s[(rbase + 8) * 132 + c4 * 4]) = y0r1;
    #pragma unroll
    for (int j = 0; j < 8; ++j)
        *reinterpret_cast<uint4*>(&y1s[(rbase + 8 * j) * 132 + c4 * 4]) = R[j];
    // issue chunk-1 gathers (fly during compute of chunk 0)
    #pragma unroll
    for (int j = 0; j < 8; ++j)
        R[j] = *reinterpret_cast<const uint4*>(&y1[(size_t)il1[j] * 128 + c4 * 4]);
    __syncthreads(); // stage 0 visible

    uint4* gblk = gated + (size_t)blockIdx.x * 3072;
    float s[8] = {0,0,0,0,0,0,0,0}, q[8] = {0,0,0,0,0,0,0,0};
    #pragma unroll
    for (int mt = 0; mt < 3; ++mt) {
        #pragma unroll
        for (int reg = 0; reg < 4; ++reg) {
            int rl = w * 16 + quad * 4 + reg;             // local y1 row
            int m = (w * 3 + mt) * 16 + quad * 4 + reg;   // global edge row in block
            int a = m / MM;                               // local atom
            const float* y0rp = &y0s[a * 132];
            const float* y1rp = &y1s[rl * 132];
            float r[8];
            #pragma unroll
            for (int nt = 0; nt < 8; ++nt) {
                int n = nt * 16 + ln;
                r[nt] = acc[mt][nt][reg] + y0rp[n] + y1rp[n];
                s[nt] += r[nt]; q[nt] += r[nt] * r[nt];
            }
            uint4 u;
            u.x = (unsigned)f2bu(r[0]) | ((unsigned)f2bu(r[1]) << 16);
            u.y = (unsigned)f2bu(r[2]) | ((unsigned)f2bu(r[3]) << 16);
            u.z = (unsigned)f2bu(r[4]) | ((unsigned)f2bu(r[5]) << 16);
            u.w = (unsigned)f2bu(r[6]) | ((unsigned)f2bu(r[7]) << 16);
            gblk[(mt * 4 + reg) * 256 + t] = u; // coalesced per (mt,reg)
        }
        if (mt < 2) {
            __syncthreads(); // this chunk's y1s reads done
            #pragma unroll
            for (int j = 0; j < 8; ++j)
                *reinterpret_cast<uint4*>(&y1s[(rbase + 8 * j) * 132 + c4 * 4]) = R[j];
            if (mt == 0) {
                // issue chunk-2 gathers (fly during compute of chunk 1)
                #pragma unroll
                for (int j = 0; j < 8; ++j)
                    R[j] = *reinterpret_cast<const uint4*>(&y1[(size_t)il2[j] * 128 + c4 * 4]);
            }
            __syncthreads(); // next stage visible
        }
    }
    #pragma unroll
    for (int nt = 0; nt < 8; ++nt) {
        s[nt] += __shfl_xor(s[nt], 16); s[nt] += __shfl_xor(s[nt], 32);
        q[nt] += __shfl_xor(q[nt], 16); q[nt] += __shfl_xor(q[nt], 32);
    }
    __syncthreads(); // staging buffers dead -> alias as red
    float* red = reinterpret_cast<float*>(AB); // [4 waves][8 nt][16 ln][2]
    if (quad == 0) {
        #pragma unroll
        for (int nt = 0; nt < 8; ++nt) {
            red[((w * 8 + nt) * 16 + ln) * 2 + 0] = s[nt];
            red[((w * 8 + nt) * 16 + ln) * 2 + 1] = q[nt];
        }
    }
    __syncthreads();
    {
        int c = t >> 1, j = t & 1; // c in 0..127
        float v = 0.f;
        #pragma unroll
        for (int w2 = 0; w2 < 4; ++w2)
            v += red[((w2 * 8 + (c >> 4)) * 16 + (c & 15)) * 2 + j];
        // replicated stats: 64 replicas of [256] to kill atomic line contention
        int rep = (blockIdx.x & (NREP - 1)) << 8;
        atomicAdd(&stats[rep + j * 128 + c], v);
    }
}

// ---------------- bn1 fold (sums NREP replicas) ----------------
__global__ void k_sc1(const float* __restrict__ stats, const float* __restrict__ g,
                      const float* __restrict__ b, float* __restrict__ sc) {
    int c = threadIdx.x; // 128
    float s = 0.f, q = 0.f;
    for (int r = 0; r < NREP; ++r) {
        s += stats[r * 256 + c];
        q += stats[r * 256 + 128 + c];
    }
    float cnt = (float)NEDGE;
    float mean = s / cnt;
    float var = q / cnt - mean * mean;
    float inv = rsqrtf(var + EPS_BN);
    float scale = g[c] * inv;
    sc[c] = scale;
    sc[128 + c] = b[c] - mean * scale;
}

// ---------------- pass B (streaming): read gated, BN1+act, sum over neighbors ----------------
__global__ __launch_bounds__(256) void k_passBs(const uint4* __restrict__ gated,
                                                const float* __restrict__ sc,
                                                float* __restrict__ summed,
                                                float* __restrict__ stats2) {
    __shared__ unsigned short P[192 * 66]; // 25344B
    __shared__ float sred[512];
    int t = threadIdx.x;
    int n0 = blockIdx.x * 16;
    int w = t >> 6, lane = t & 63, ln = lane & 15, quad = lane >> 4;
    float scF[4], shF[4], scC[4], shC[4];
    #pragma unroll
    for (int nt = 0; nt < 4; ++nt) {
        int cc = nt * 16 + ln;
        scF[nt] = sc[cc];      shF[nt] = sc[128 + cc];
        scC[nt] = sc[64 + cc]; shC[nt] = sc[192 + cc];
    }
    const uint4* gblk = gated + (size_t)blockIdx.x * 3072;
    #pragma unroll
    for (int mt = 0; mt < 3; ++mt) {
        #pragma unroll
        for (int reg = 0; reg < 4; ++reg) {
            uint4 u = gblk[(mt * 4 + reg) * 256 + t];
            int m = (w * 3 + mt) * 16 + quad * 4 + reg;
            unsigned uu[4] = {u.x, u.y, u.z, u.w};
            #pragma unroll
            for (int nt = 0; nt < 4; ++nt) {
                // filter col from uu[nt>>1] halves (nt), core from uu[2+(nt>>1)]
                float rfv = u2f((unsigned short)((nt & 1) ? (uu[nt >> 1] >> 16) : (uu[nt >> 1] & 0xffff)));
                float rcv = u2f((unsigned short)((nt & 1) ? (uu[2 + (nt >> 1)] >> 16) : (uu[2 + (nt >> 1)] & 0xffff)));
                float rf = rfv * scF[nt] + shF[nt];
                float rc = rcv * scC[nt] + shC[nt];
                P[m * 66 + nt * 16 + ln] = f2bu(fsigmoid(rf) * fsoftplus(rc));
            }
        }
    }
    __syncthreads();
    int cc = t & 63, who = t >> 6;
    float sA = 0.f, qA = 0.f;
    #pragma unroll
    for (int k2 = 0; k2 < 4; ++k2) {
        int a = who + k2 * 4;
        float v = 0.f;
        #pragma unroll
        for (int j = 0; j < 12; ++j) v += u2f(P[(a * 12 + j) * 66 + cc]);
        summed[(size_t)(n0 + a) * AA + cc] = v;
        sA += v; qA += v * v;
    }
    sred[who * 64 + cc] = sA;
    sred[256 + who * 64 + cc] = qA;
    __syncthreads();
    if (t < 64) {
        float s4 = sred[t] + sred[64 + t] + sred[128 + t] + sred[192 + t];
        float q4 = sred[256 + t] + sred[320 + t] + sred[384 + t] + sred[448 + t];
        int rep = (blockIdx.x & (NREP - 1)) << 7; // replicas of [128]
        atomicAdd(&stats2[rep + t], s4);
        atomicAdd(&stats2[rep + 64 + t], q4);
    }
}

// NOTE on passA/passBs packing: uint u.x={nt0,nt1}, u.y={nt2,nt3} (filter cols nt*16+ln),
// u.z={nt4,nt5}, u.w={nt6,nt7} (core cols 64+...). passBs mapping above matches:
// filter nt -> uu[nt>>1], core nt -> uu[2+(nt>>1)].

// ---------------- bn2 fold (sums NREP replicas) ----------------
__global__ void k_sc2(const float* __restrict__ stats2, const float* __restrict__ g,
                      const float* __restrict__ b, float* __restrict__ sc2) {
    int c = threadIdx.x; // 64
    float s = 0.f, q = 0.f;
    for (int r = 0; r < NREP; ++r) {
        s += stats2[r * 128 + c];
        q += stats2[r * 128 + 64 + c];
    }
    float cnt = (float)NATOM;
    float mean = s / cnt;
    float var = q / cnt - mean * mean;
    float inv = rsqrtf(var + EPS_BN);
    float scale = g[c] * inv;
    sc2[c] = scale;
    sc2[64 + c] = b[c] - mean * scale;
}

// ---------------- x = softplus(x + bn2(summed)) ----------------
__global__ void k_update(float* __restrict__ x, const float* __restrict__ summed,
                         const float* __restrict__ sc2) {
    int i = blockIdx.x * blockDim.x + threadIdx.x;
    if (i < NATOM * AA) {
        int c = i & 63;
        float s = summed[i] * sc2[c] + sc2[64 + c];
        x[i] = fsoftplus(x[i] + s);
    }
}

// ---------------- bilinear head via MFMA: T = CF @ Bq^T-layout, q, fc1, log_softmax ----------------
__global__ __launch_bounds__(256) void k_q(const float* __restrict__ x, const int* __restrict__ cidx,
                                           const unsigned short* __restrict__ Bq, // 384x72 bf16
                                           const float* __restrict__ adjb,
                                           const float* __restrict__ fc1w,
                                           const float* __restrict__ fc1b,
                                           float* __restrict__ logp) {
    __shared__ __attribute__((aligned(16))) unsigned short Aq[64 * 72];  // 9216B
    __shared__ __attribute__((aligned(16))) unsigned short Bl[384 * 72]; // 55296B
    __shared__ float qv[64][6];
    int t = threadIdx.x;
    int p0 = blockIdx.x * 64;
    for (int i = t; i < 64 * 72; i += 256) {
        int a = i / 72, k = i - a * 72;
        int ga = p0 + a;
        float v = (k < 64 && ga < NATOM) ? x[(size_t)cidx[ga < NATOM ? ga : 0] * AA + k] : 0.f;
        Aq[i] = f2bu(v);
    }
    for (int i = t; i < 3456; i += 256)
        reinterpret_cast<uint4*>(Bl)[i] = reinterpret_cast<const uint4*>(Bq)[i];
    __syncthreads();

    int w = t >> 6, lane = t & 63, ln = lane & 15, quad = lane >> 4;
    f32x4 acc[24];
    f32x4 z4 = {0.f, 0.f, 0.f, 0.f};
    #pragma unroll
    for (int i = 0; i < 24; ++i) acc[i] = z4;
    {
        int mrow = w * 16 + ln;
        s16x8 a0 = *reinterpret_cast<const s16x8*>(&Aq[mrow * 72 + quad * 8]);
        s16x8 a1 = *reinterpret_cast<const s16x8*>(&Aq[mrow * 72 + quad * 8 + 32]);
        #pragma unroll
        for (int nt = 0; nt < 24; ++nt) {
            int nrow = nt * 16 + ln;
            s16x8 b0 = *reinterpret_cast<const s16x8*>(&Bl[nrow * 72 + quad * 8]);
            s16x8 b1 = *reinterpret_cast<const s16x8*>(&Bl[nrow * 72 + quad * 8 + 32]);
            acc[nt] = __builtin_amdgcn_mfma_f32_16x16x32_bf16(a0, b0, acc[nt], 0, 0, 0);
            acc[nt] = __builtin_amdgcn_mfma_f32_16x16x32_bf16(a1, b1, acc[nt], 0, 0, 0);
        }
    }
    // epilogue: q[a][o] = sum_e T[a][o*64+e] * cf[a][e]
    float cfv[4][4];
    #pragma unroll
    for (int reg = 0; reg < 4; ++reg) {
        int ga = p0 + w * 16 + quad * 4 + reg;
        const float* xr = x + (size_t)cidx[ga < NATOM ? ga : 0] * AA;
        #pragma unroll
        for (int et = 0; et < 4; ++et)
            cfv[reg][et] = (ga < NATOM) ? xr[et * 16 + ln] : 0.f;
    }
    float bo[6];
    #pragma unroll
    for (int o = 0; o < 6; ++o) bo[o] = adjb[o];
    #pragma unroll
    for (int reg = 0; reg < 4; ++reg) {
        #pragma unroll
        for (int o = 0; o < 6; ++o) {
            float p = 0.f;
            #pragma unroll
            for (int et = 0; et < 4; ++et)
                p += acc[o * 4 + et][reg] * cfv[reg][et];
            p += __shfl_xor(p, 1); p += __shfl_xor(p, 2);
            p += __shfl_xor(p, 4); p += __shfl_xor(p, 8);
            if (ln == 0) qv[w * 16 + quad * 4 + reg][o] = p + bo[o];
        }
    }
    __syncthreads();
    if (t < 64) {
        int ga = p0 + t;
        if (ga < NATOM) {
            float q2[6];
            float mx = -1e30f;
            #pragma unroll
            for (int o2 = 0; o2 < 6; ++o2) {
                float acc2 = fc1b[o2];
                #pragma unroll
                for (int o = 0; o < 6; ++o) acc2 += qv[t][o] * fc1w[o * 6 + o2];
                q2[o2] = acc2; mx = fmaxf(mx, acc2);
            }
            float se = 0.f;
            #pragma unroll
            for (int o2 = 0; o2 < 6; ++o2) se += __expf(q2[o2] - mx);
            float lse = mx + __logf(se);
            #pragma unroll
            for (int o2 = 0; o2 < 6; ++o2) logp[(size_t)ga * 6 + o2] = q2[o2] - lse;
        }
    }
}

// ---------------- edge_prob broadcast write ----------------
__global__ void k_edge(const float* __restrict__ logp, float* __restrict__ out0) {
    int i4 = blockIdx.x * blockDim.x + threadIdx.x;
    if (i4 >= (NB * NPCC * NPCC * 6) / 4) return;
    int e = i4 * 4;
    int b = e / (NPCC * NPCC * 6);
    int rr = e - b * (NPCC * NPCC * 6);
    const float* lb = &logp[(size_t)b * NPCC * 6];
    float4 v;
    int r0 = rr % 300;       v.x = lb[r0];
    int r1 = (rr + 1) % 300; v.y = lb[r1];
    int r2 = (rr + 2) % 300; v.z = lb[r2];
    int r3 = (rr + 3) % 300; v.w = lb[r3];
    *reinterpret_cast<float4*>(&out0[e]) = v;
}

// ---------------- atom_feature = cf @ af_w + af_b ----------------
__global__ __launch_bounds__(256) void k_af(const float* __restrict__ x, const int* __restrict__ cidx,
                                            const float* __restrict__ afw,
                                            const float* __restrict__ afb,
                                            float* __restrict__ out1) {
    __shared__ float wl[AA * ORIGD];
    __shared__ float cfl[2][AA];
    int t = threadIdx.x;
    for (int i = t; i < AA * ORIGD; i += 256) wl[i] = afw[i];
    int p0 = blockIdx.x * 2;
    if (t < 128) {
        int a = t >> 6, e = t & 63;
        cfl[a][e] = x[(size_t)cidx[p0 + a] * AA + e];
    }
    __syncthreads();
    int a = t >> 7, c = t & 127;
    if (c < ORIGD) {
        float acc = afb[c];
        #pragma unroll 8
        for (int k = 0; k < AA; ++k)
            acc += cfl[a][k] * wl[k * ORIGD + c];
        out1[(size_t)(p0 + a) * ORIGD + c] = acc;
    }
}

extern "C" void kernel_launch(void* const* d_in, const int* in_sizes, int n_in,
                              void* d_out, int out_size, void* d_ws, size_t ws_size,
                              hipStream_t stream) {
    (void)in_sizes; (void)n_in; (void)out_size; (void)ws_size;
    const float* atom_fea  = (const float*)d_in[0];
    const float* nbr_fea   = (const float*)d_in[1];
    const int*   nbr_idx   = (const int*)d_in[2];
    const int*   cidx      = (const int*)d_in[3];
    const float* emb_w     = (const float*)d_in[4];
    const float* fc_full_w = (const float*)d_in[5];
    // d_in[6] fc_full_b: cancelled by batchnorm
    const float* bn1_g = (const float*)d_in[7];
    const float* bn1_b = (const float*)d_in[8];
    const float* bn2_g = (const float*)d_in[9];
    const float* bn2_b = (const float*)d_in[10];
    const float* adj_w = (const float*)d_in[11];
    const float* adj_b = (const float*)d_in[12];
    const float* fc1_w = (const float*)d_in[13];
    const float* fc1_b = (const float*)d_in[14];
    const float* af_w  = (const float*)d_in[15];
    const float* af_b  = (const float*)d_in[16];

    float* out0 = (float*)d_out;
    float* out1 = out0 + (size_t)NB * NPCC * NPCC * 6;

    float* ws = (float*)d_ws;
    float* x      = ws;
    float* y0     = x + (size_t)NATOM * AA;
    float* y1     = y0 + (size_t)NATOM * 128;
    float* summed = y1 + (size_t)NATOM * 128;
    float* logp   = summed + (size_t)NATOM * AA;
    float* stats1 = logp + (size_t)NATOM * 6;          // [NREP][256]
    float* stats2 = stats1 + (size_t)NREP * 256;       // [NREP][128]
    float* sc1    = stats2 + (size_t)NREP * 128;       // [256]
    float* sc2    = sc1 + 256;                         // [128]
    float* endf   = sc2 + 128;
    size_t off = (((size_t)((char*)endf - (char*)d_ws)) + 255) & ~(size_t)255;
    unsigned short* Bt = (unsigned short*)((char*)d_ws + off);   // 128*72 bf16
    unsigned short* Bq = Bt + 128 * 72;                          // 384*72 bf16
    size_t goff = (off + (128 * 72 + 384 * 72) * 2 + 255) & ~(size_t)255;
    uint4* gated = (uint4*)((char*)d_ws + goff);                 // 3125*3072 uint4 = 153.6MB

    const int nstat = NREP * 256 + NREP * 128; // 24576 floats
    k_embed<<<NATOM / 4, 256, 0, stream>>>(atom_fea, emb_w, x);
    k_prepQ<<<108, 256, 0, stream>>>(adj_w, Bq);
    for (int layer = 0; layer < 3; ++layer) {
        const float* W  = fc_full_w + (size_t)layer * 169 * 128;
        const float* W2 = W + 128 * 128;
        k_zero<<<(nstat + 255) / 256, 256, 0, stream>>>(stats1, nstat);
        k_prepB<<<1, 256, 0, stream>>>(W2, Bt);
        k_y01<<<NATOM / 16, 256, 0, stream>>>(x, W, y0, y1);
        k_passA<<<NATOM / 16, 256, 0, stream>>>(y0, y1, nbr_fea, Bt, nbr_idx, stats1, gated);
        k_sc1<<<1, 128, 0, stream>>>(stats1, bn1_g + layer * 128, bn1_b + layer * 128, sc1);
        k_passBs<<<NATOM / 16, 256, 0, stream>>>(gated, sc1, summed, stats2);
        k_sc2<<<1, 64, 0, stream>>>(stats2, bn2_g + layer * 64, bn2_b + layer * 64, sc2);
        k_update<<<(NATOM * AA + 255) / 256, 256, 0, stream>>>(x, summed, sc2);
    }
    k_q<<<(NATOM + 63) / 64, 256, 0, stream>>>(x, cidx, Bq, adj_b, fc1_w, fc1_b, logp);
    k_edge<<<((NB * NPCC * NPCC * 6) / 4 + 255) / 256, 256, 0, stream>>>(logp, out0);
    k_af<<<NATOM / 2, 256, 0, stream>>>(x, cidx, af_w, af_b, out1);
}

// Round 4
// 949.411 us; speedup vs baseline: 1.3854x; 1.3854x over previous
//
#include <hip/hip_runtime.h>
#include <hip/hip_bf16.h>

#define AA 64
#define NBRF 41
#define ORIGD 92
#define NATOM 50000
#define MM 12
#define NB 1000
#define NPCC 50
#define NEDGE (NATOM*MM)
#define NREP 64
constexpr float EPS_BN = 1e-5f;

using bf16 = __hip_bfloat16;
typedef short s16x8 __attribute__((ext_vector_type(8)));
typedef float f32x4 __attribute__((ext_vector_type(4)));

__device__ __forceinline__ float u2f(unsigned short u) {
    union { float f; unsigned int i; } v; v.i = ((unsigned int)u) << 16; return v.f;
}
__device__ __forceinline__ unsigned short f2bu(float f) {
    bf16 h = __float2bfloat16(f);
    return *reinterpret_cast<unsigned short*>(&h);
}
__device__ __forceinline__ float fsigmoid(float x) {
    float e = __expf(-x);
    return __builtin_amdgcn_rcpf(1.f + e);
}
__device__ __forceinline__ float fsoftplus(float x) {
    return fmaxf(x, 0.f) + __logf(1.f + __expf(-fabsf(x)));
}

// global->LDS direct DMA, 16B per lane, lane l lands at lds + l*16
#define GLD16(g, l)                                                              \
    __builtin_amdgcn_global_load_lds(                                            \
        (const __attribute__((address_space(1))) unsigned int*)(g),              \
        (__attribute__((address_space(3))) unsigned int*)(l), 16, 0, 0)

// ---------------- merged: zero stats + prep W2^T -> bf16 [128][72] ----------------
__global__ void k_prep0(const float* __restrict__ W2, unsigned short* __restrict__ Bt,
                        float* __restrict__ stats, int nstat) {
    int b = blockIdx.x, t = threadIdx.x;
    if (b == 0) {
        for (int i = t; i < 128 * 72; i += 256) {
            int n = i / 72, kk = i - n * 72;
            float v = (kk < NBRF) ? W2[kk * 128 + n] : 0.f;
            Bt[i] = f2bu(v);
        }
    } else {
        int base = (b - 1) * 2048;
        for (int i = t; i < 2048; i += 256) {
            int idx = base + i;
            if (idx < nstat) stats[idx] = 0.f;
        }
    }
}

// ---------------- prep: adj_w -> Bq bf16 [384 rows(n=o*64+e)][72 (k=d, padded)] ----------------
__global__ void k_prepQ(const float* __restrict__ adjw, unsigned short* __restrict__ Bq) {
    int i = blockIdx.x * 256 + threadIdx.x; // 384*72 = 27648
    if (i >= 384 * 72) return;
    int n = i / 72, k = i - n * 72;
    float v = (k < 64) ? adjw[(n >> 6) * 4096 + k * 64 + (n & 63)] : 0.f;
    Bq[i] = f2bu(v);
}

// ---------------- embed: x = atom_fea @ emb_w  (N,92)@(92,64) ----------------
__global__ __launch_bounds__(256) void k_embed(const float* __restrict__ af,
                                               const float* __restrict__ w,
                                               float* __restrict__ x) {
    __shared__ float wl[ORIGD * AA];
    __shared__ float al[4][ORIGD];
    int t = threadIdx.x;
    for (int i = t; i < ORIGD * AA; i += 256) wl[i] = w[i];
    int n0 = blockIdx.x * 4;
    for (int i = t; i < 4 * ORIGD; i += 256) {
        int a = i / ORIGD, k = i - a * ORIGD;
        al[a][k] = af[(size_t)(n0 + a) * ORIGD + k];
    }
    __syncthreads();
    int c = t & 63, a = t >> 6;
    float acc = 0.f;
    #pragma unroll 4
    for (int k = 0; k < ORIGD; ++k)
        acc += al[a][k] * wl[k * AA + c];
    x[(size_t)(n0 + a) * AA + c] = acc;
}

// ---------------- y0 = x@W[0:64], y1 = x@W[64:128] ----------------
__global__ __launch_bounds__(256) void k_y01(const float* __restrict__ x,
                                             const float* __restrict__ W, // 169x128 layer base
                                             float* __restrict__ y0, float* __restrict__ y1) {
    __shared__ float wl[64 * 128];
    __shared__ float xl[16][AA];
    int t = threadIdx.x;
    int n0 = blockIdx.x * 16;
    for (int i = t; i < 16 * AA; i += 256) {
        int a = i >> 6, k = i & 63;
        xl[a][k] = x[(size_t)(n0 + a) * AA + k];
    }
    int tc = t & 31, sub = t >> 5;
    int c0 = tc * 4;
    for (int half = 0; half < 2; ++half) {
        if (half) __syncthreads();
        const float* Wh = W + (size_t)half * 64 * 128;
        for (int i = t; i < 64 * 128; i += 256) wl[i] = Wh[i];
        __syncthreads();
        float* yout = half ? y1 : y0;
        for (int ah = 0; ah < 2; ++ah) {
            int a = sub + ah * 8;
            float a0=0,a1=0,a2=0,a3=0;
            #pragma unroll 8
            for (int k = 0; k < AA; ++k) {
                float xv = xl[a][k];
                float4 w4 = *reinterpret_cast<const float4*>(&wl[k * 128 + c0]);
                a0 += xv * w4.x; a1 += xv * w4.y; a2 += xv * w4.z; a3 += xv * w4.w;
            }
            float4 r = {a0,a1,a2,a3};
            *reinterpret_cast<float4*>(&yout[(size_t)(n0 + a) * 128 + c0]) = r;
        }
    }
}

// ================= MFMA edge-GEMM pass A =================
// Per block: 16 atoms -> 192 edges. [192 x 64pad] @ [64pad x 128] bf16.
// Epilogue v4: wave-private staging via global_load_lds (no VGPR residency,
// no block barriers). Wave w consumes only y1 rows [16w,16w+16) and y0 atoms
// [4w,4w+4); pair-packed LDS layout [pair][264] keeps DMA dest linear and
// epilogue reads at 2 lanes/bank (free).

#define MFMA_LOOP(acc, Al, Bl, w, ln, quad)                                         \
    _Pragma("unroll")                                                               \
    for (int mt = 0; mt < 3; ++mt) {                                                \
        int mrow = ((w) * 3 + mt) * 16 + (ln);                                      \
        s16x8 a0 = *reinterpret_cast<const s16x8*>(&(Al)[mrow * 72 + (quad) * 8]);  \
        s16x8 a1 = *reinterpret_cast<const s16x8*>(&(Al)[mrow * 72 + (quad) * 8 + 32]); \
        _Pragma("unroll")                                                           \
        for (int nt = 0; nt < 8; ++nt) {                                            \
            int nrow = nt * 16 + (ln);                                              \
            s16x8 b0 = *reinterpret_cast<const s16x8*>(&(Bl)[nrow * 72 + (quad) * 8]);      \
            s16x8 b1 = *reinterpret_cast<const s16x8*>(&(Bl)[nrow * 72 + (quad) * 8 + 32]); \
            acc[mt][nt] = __builtin_amdgcn_mfma_f32_16x16x32_bf16(a0, b0, acc[mt][nt], 0, 0, 0); \
            acc[mt][nt] = __builtin_amdgcn_mfma_f32_16x16x32_bf16(a1, b1, acc[mt][nt], 0, 0, 0); \
        }                                                                           \
    }

__global__ __launch_bounds__(256, 3) void k_passA(const float* __restrict__ y0,
                                                  const float* __restrict__ y1,
                                                  const float* __restrict__ nf,
                                                  const unsigned short* __restrict__ Bt,
                                                  const int* __restrict__ nidx,
                                                  float* __restrict__ stats,
                                                  uint4* __restrict__ gated) {
    // Al 192*72 (27648B) + Bl 128*72 (18432B) = 46080B, aliased in epilogue as
    // y1s[32 pairs][264] (33792B) + y0s[8 pairs][264] (8448B), then red[1024] f32.
    __shared__ __attribute__((aligned(16))) unsigned short AB[192 * 72 + 128 * 72];
    __shared__ int il[192];
    unsigned short* Al = AB;
    unsigned short* Bl = AB + 192 * 72;
    int t = threadIdx.x;
    int n0 = blockIdx.x * 16;
    {
        const float* fg = nf + (size_t)n0 * MM * NBRF;
        #pragma unroll 4
        for (int i = t; i < 192 * NBRF; i += 256) {
            int m = i / NBRF, k = i - m * NBRF;
            Al[m * 72 + k] = f2bu(fg[i]);
        }
        #pragma unroll
        for (int i = t; i < 192 * 23; i += 256) {
            int m = i / 23, k = 41 + (i - m * 23);
            Al[m * 72 + k] = 0;
        }
        #pragma unroll 4
        for (int i = t; i < 128 * 9; i += 256)
            reinterpret_cast<uint4*>(Bl)[i] = reinterpret_cast<const uint4*>(Bt)[i];
        if (t < 192) il[t] = nidx[n0 * MM + t];
    }
    __syncthreads();

    int w = t >> 6, lane = t & 63, ln = lane & 15, quad = lane >> 4;
    f32x4 acc[3][8];
    f32x4 z4 = {0.f, 0.f, 0.f, 0.f};
    for (int i = 0; i < 3; ++i) for (int j = 0; j < 8; ++j) acc[i][j] = z4;
    MFMA_LOOP(acc, Al, Bl, w, ln, quad);
    __syncthreads(); // Al/Bl dead -> alias as wave-private staging buffers

    float* y1s = reinterpret_cast<float*>(AB);   // 32 pairs x 264 floats
    float* y0s = y1s + 32 * 264;                 // 8 pairs x 264 floats
    int l32 = lane & 31, lh = lane >> 5;

    // stage y0: wave w owns pairs {2w, 2w+1} = atoms [4w, 4w+4)
    #pragma unroll
    for (int pp = 0; pp < 2; ++pp) {
        int pr = w * 2 + pp;
        GLD16(&y0[(size_t)(n0 + pr * 2 + lh) * 128 + l32 * 4], &y0s[pr * 264]);
    }

    uint4* gblk = gated + (size_t)blockIdx.x * 3072;
    float s[8] = {0,0,0,0,0,0,0,0}, q[8] = {0,0,0,0,0,0,0,0};
    #pragma unroll
    for (int mt = 0; mt < 3; ++mt) {
        // issue this chunk's 8 pair-gathers (wave-private region, no barrier)
        #pragma unroll
        for (int j = 0; j < 8; ++j) {
            int m = w * 48 + mt * 16 + 2 * j + lh;
            int idx = il[m];
            GLD16(&y1[(size_t)idx * 128 + l32 * 4], &y1s[(w * 8 + j) * 264]);
        }
        asm volatile("s_waitcnt vmcnt(0)" ::: "memory");
        __builtin_amdgcn_sched_barrier(0);
        #pragma unroll
        for (int reg = 0; reg < 4; ++reg) {
            int rl = w * 16 + quad * 4 + reg;             // local y1 row
            int m = (w * 3 + mt) * 16 + quad * 4 + reg;   // edge row in block
            int a = m / MM;                               // local atom
            const float* y0rp = &y0s[(a >> 1) * 264 + (a & 1) * 128];
            const float* y1rp = &y1s[(rl >> 1) * 264 + (rl & 1) * 128];
            float r[8];
            #pragma unroll
            for (int nt = 0; nt < 8; ++nt) {
                int n = nt * 16 + ln;
                r[nt] = acc[mt][nt][reg] + y0rp[n] + y1rp[n];
                s[nt] += r[nt]; q[nt] += r[nt] * r[nt];
            }
            uint4 u;
            u.x = (unsigned)f2bu(r[0]) | ((unsigned)f2bu(r[1]) << 16);
            u.y = (unsigned)f2bu(r[2]) | ((unsigned)f2bu(r[3]) << 16);
            u.z = (unsigned)f2bu(r[4]) | ((unsigned)f2bu(r[5]) << 16);
            u.w = (unsigned)f2bu(r[6]) | ((unsigned)f2bu(r[7]) << 16);
            gblk[(mt * 4 + reg) * 256 + t] = u; // coalesced per (mt,reg)
        }
    }
    #pragma unroll
    for (int nt = 0; nt < 8; ++nt) {
        s[nt] += __shfl_xor(s[nt], 16); s[nt] += __shfl_xor(s[nt], 32);
        q[nt] += __shfl_xor(q[nt], 16); q[nt] += __shfl_xor(q[nt], 32);
    }
    __syncthreads(); // staging buffers dead -> alias as red
    float* red = reinterpret_cast<float*>(AB); // [4 waves][8 nt][16 ln][2]
    if (quad == 0) {
        #pragma unroll
        for (int nt = 0; nt < 8; ++nt) {
            red[((w * 8 + nt) * 16 + ln) * 2 + 0] = s[nt];
            red[((w * 8 + nt) * 16 + ln) * 2 + 1] = q[nt];
        }
    }
    __syncthreads();
    {
        int c = t >> 1, j = t & 1; // c in 0..127
        float v = 0.f;
        #pragma unroll
        for (int w2 = 0; w2 < 4; ++w2)
            v += red[((w2 * 8 + (c >> 4)) * 16 + (c & 15)) * 2 + j];
        int rep = (blockIdx.x & (NREP - 1)) << 8;
        atomicAdd(&stats[rep + j * 128 + c], v);
    }
}

// ---------------- bn1 fold (sums NREP replicas) ----------------
__global__ void k_sc1(const float* __restrict__ stats, const float* __restrict__ g,
                      const float* __restrict__ b, float* __restrict__ sc) {
    int c = threadIdx.x; // 128
    float s = 0.f, q = 0.f;
    for (int r = 0; r < NREP; ++r) {
        s += stats[r * 256 + c];
        q += stats[r * 256 + 128 + c];
    }
    float cnt = (float)NEDGE;
    float mean = s / cnt;
    float var = q / cnt - mean * mean;
    float inv = rsqrtf(var + EPS_BN);
    float scale = g[c] * inv;
    sc[c] = scale;
    sc[128 + c] = b[c] - mean * scale;
}

// ---------------- pass B (streaming): read gated, BN1+act, sum over neighbors ----------------
__global__ __launch_bounds__(256) void k_passBs(const uint4* __restrict__ gated,
                                                const float* __restrict__ sc,
                                                float* __restrict__ summed,
                                                float* __restrict__ stats2) {
    __shared__ unsigned short P[192 * 66]; // 25344B
    __shared__ float sred[512];
    int t = threadIdx.x;
    int n0 = blockIdx.x * 16;
    int w = t >> 6, lane = t & 63, ln = lane & 15, quad = lane >> 4;
    float scF[4], shF[4], scC[4], shC[4];
    #pragma unroll
    for (int nt = 0; nt < 4; ++nt) {
        int cc = nt * 16 + ln;
        scF[nt] = sc[cc];      shF[nt] = sc[128 + cc];
        scC[nt] = sc[64 + cc]; shC[nt] = sc[192 + cc];
    }
    const uint4* gblk = gated + (size_t)blockIdx.x * 3072;
    #pragma unroll
    for (int mt = 0; mt < 3; ++mt) {
        #pragma unroll
        for (int reg = 0; reg < 4; ++reg) {
            uint4 u = gblk[(mt * 4 + reg) * 256 + t];
            int m = (w * 3 + mt) * 16 + quad * 4 + reg;
            unsigned uu[4] = {u.x, u.y, u.z, u.w};
            #pragma unroll
            for (int nt = 0; nt < 4; ++nt) {
                float rfv = u2f((unsigned short)((nt & 1) ? (uu[nt >> 1] >> 16) : (uu[nt >> 1] & 0xffff)));
                float rcv = u2f((unsigned short)((nt & 1) ? (uu[2 + (nt >> 1)] >> 16) : (uu[2 + (nt >> 1)] & 0xffff)));
                float rf = rfv * scF[nt] + shF[nt];
                float rc = rcv * scC[nt] + shC[nt];
                P[m * 66 + nt * 16 + ln] = f2bu(fsigmoid(rf) * fsoftplus(rc));
            }
        }
    }
    __syncthreads();
    int cc = t & 63, who = t >> 6;
    float sA = 0.f, qA = 0.f;
    #pragma unroll
    for (int k2 = 0; k2 < 4; ++k2) {
        int a = who + k2 * 4;
        float v = 0.f;
        #pragma unroll
        for (int j = 0; j < 12; ++j) v += u2f(P[(a * 12 + j) * 66 + cc]);
        summed[(size_t)(n0 + a) * AA + cc] = v;
        sA += v; qA += v * v;
    }
    sred[who * 64 + cc] = sA;
    sred[256 + who * 64 + cc] = qA;
    __syncthreads();
    if (t < 64) {
        float s4 = sred[t] + sred[64 + t] + sred[128 + t] + sred[192 + t];
        float q4 = sred[256 + t] + sred[320 + t] + sred[384 + t] + sred[448 + t];
        int rep = (blockIdx.x & (NREP - 1)) << 7; // replicas of [128]
        atomicAdd(&stats2[rep + t], s4);
        atomicAdd(&stats2[rep + 64 + t], q4);
    }
}

// ---------------- bn2 fold (sums NREP replicas) ----------------
__global__ void k_sc2(const float* __restrict__ stats2, const float* __restrict__ g,
                      const float* __restrict__ b, float* __restrict__ sc2) {
    int c = threadIdx.x; // 64
    float s = 0.f, q = 0.f;
    for (int r = 0; r < NREP; ++r) {
        s += stats2[r * 128 + c];
        q += stats2[r * 128 + 64 + c];
    }
    float cnt = (float)NATOM;
    float mean = s / cnt;
    float var = q / cnt - mean * mean;
    float inv = rsqrtf(var + EPS_BN);
    float scale = g[c] * inv;
    sc2[c] = scale;
    sc2[64 + c] = b[c] - mean * scale;
}

// ---------------- x = softplus(x + bn2(summed)) ----------------
__global__ void k_update(float* __restrict__ x, const float* __restrict__ summed,
                         const float* __restrict__ sc2) {
    int i = blockIdx.x * blockDim.x + threadIdx.x;
    if (i < NATOM * AA) {
        int c = i & 63;
        float s = summed[i] * sc2[c] + sc2[64 + c];
        x[i] = fsoftplus(x[i] + s);
    }
}

// ---------------- bilinear head via MFMA ----------------
__global__ __launch_bounds__(256) void k_q(const float* __restrict__ x, const int* __restrict__ cidx,
                                           const unsigned short* __restrict__ Bq, // 384x72 bf16
                                           const float* __restrict__ adjb,
                                           const float* __restrict__ fc1w,
                                           const float* __restrict__ fc1b,
                                           float* __restrict__ logp) {
    __shared__ __attribute__((aligned(16))) unsigned short Aq[64 * 72];  // 9216B
    __shared__ __attribute__((aligned(16))) unsigned short Bl[384 * 72]; // 55296B
    __shared__ float qv[64][6];
    int t = threadIdx.x;
    int p0 = blockIdx.x * 64;
    for (int i = t; i < 64 * 72; i += 256) {
        int a = i / 72, k = i - a * 72;
        int ga = p0 + a;
        float v = (k < 64 && ga < NATOM) ? x[(size_t)cidx[ga < NATOM ? ga : 0] * AA + k] : 0.f;
        Aq[i] = f2bu(v);
    }
    for (int i = t; i < 3456; i += 256)
        reinterpret_cast<uint4*>(Bl)[i] = reinterpret_cast<const uint4*>(Bq)[i];
    __syncthreads();

    int w = t >> 6, lane = t & 63, ln = lane & 15, quad = lane >> 4;
    f32x4 acc[24];
    f32x4 z4 = {0.f, 0.f, 0.f, 0.f};
    #pragma unroll
    for (int i = 0; i < 24; ++i) acc[i] = z4;
    {
        int mrow = w * 16 + ln;
        s16x8 a0 = *reinterpret_cast<const s16x8*>(&Aq[mrow * 72 + quad * 8]);
        s16x8 a1 = *reinterpret_cast<const s16x8*>(&Aq[mrow * 72 + quad * 8 + 32]);
        #pragma unroll
        for (int nt = 0; nt < 24; ++nt) {
            int nrow = nt * 16 + ln;
            s16x8 b0 = *reinterpret_cast<const s16x8*>(&Bl[nrow * 72 + quad * 8]);
            s16x8 b1 = *reinterpret_cast<const s16x8*>(&Bl[nrow * 72 + quad * 8 + 32]);
            acc[nt] = __builtin_amdgcn_mfma_f32_16x16x32_bf16(a0, b0, acc[nt], 0, 0, 0);
            acc[nt] = __builtin_amdgcn_mfma_f32_16x16x32_bf16(a1, b1, acc[nt], 0, 0, 0);
        }
    }
    float cfv[4][4];
    #pragma unroll
    for (int reg = 0; reg < 4; ++reg) {
        int ga = p0 + w * 16 + quad * 4 + reg;
        const float* xr = x + (size_t)cidx[ga < NATOM ? ga : 0] * AA;
        #pragma unroll
        for (int et = 0; et < 4; ++et)
            cfv[reg][et] = (ga < NATOM) ? xr[et * 16 + ln] : 0.f;
    }
    float bo[6];
    #pragma unroll
    for (int o = 0; o < 6; ++o) bo[o] = adjb[o];
    #pragma unroll
    for (int reg = 0; reg < 4; ++reg) {
        #pragma unroll
        for (int o = 0; o < 6; ++o) {
            float p = 0.f;
            #pragma unroll
            for (int et = 0; et < 4; ++et)
                p += acc[o * 4 + et][reg] * cfv[reg][et];
            p += __shfl_xor(p, 1); p += __shfl_xor(p, 2);
            p += __shfl_xor(p, 4); p += __shfl_xor(p, 8);
            if (ln == 0) qv[w * 16 + quad * 4 + reg][o] = p + bo[o];
        }
    }
    __syncthreads();
    if (t < 64) {
        int ga = p0 + t;
        if (ga < NATOM) {
            float q2[6];
            float mx = -1e30f;
            #pragma unroll
            for (int o2 = 0; o2 < 6; ++o2) {
                float acc2 = fc1b[o2];
                #pragma unroll
                for (int o = 0; o < 6; ++o) acc2 += qv[t][o] * fc1w[o * 6 + o2];
                q2[o2] = acc2; mx = fmaxf(mx, acc2);
            }
            float se = 0.f;
            #pragma unroll
            for (int o2 = 0; o2 < 6; ++o2) se += __expf(q2[o2] - mx);
            float lse = mx + __logf(se);
            #pragma unroll
            for (int o2 = 0; o2 < 6; ++o2) logp[(size_t)ga * 6 + o2] = q2[o2] - lse;
        }
    }
}

// ---------------- edge_prob broadcast write ----------------
__global__ void k_edge(const float* __restrict__ logp, float* __restrict__ out0) {
    int i4 = blockIdx.x * blockDim.x + threadIdx.x;
    if (i4 >= (NB * NPCC * NPCC * 6) / 4) return;
    int e = i4 * 4;
    int b = e / (NPCC * NPCC * 6);
    int rr = e - b * (NPCC * NPCC * 6);
    const float* lb = &logp[(size_t)b * NPCC * 6];
    float4 v;
    int r0 = rr % 300;       v.x = lb[r0];
    int r1 = (rr + 1) % 300; v.y = lb[r1];
    int r2 = (rr + 2) % 300; v.z = lb[r2];
    int r3 = (rr + 3) % 300; v.w = lb[r3];
    *reinterpret_cast<float4*>(&out0[e]) = v;
}

// ---------------- atom_feature = cf @ af_w + af_b ----------------
__global__ __launch_bounds__(256) void k_af(const float* __restrict__ x, const int* __restrict__ cidx,
                                            const float* __restrict__ afw,
                                            const float* __restrict__ afb,
                                            float* __restrict__ out1) {
    __shared__ float wl[AA * ORIGD];
    __shared__ float cfl[2][AA];
    int t = threadIdx.x;
    for (int i = t; i < AA * ORIGD; i += 256) wl[i] = afw[i];
    int p0 = blockIdx.x * 2;
    if (t < 128) {
        int a = t >> 6, e = t & 63;
        cfl[a][e] = x[(size_t)cidx[p0 + a] * AA + e];
    }
    __syncthreads();
    int a = t >> 7, c = t & 127;
    if (c < ORIGD) {
        float acc = afb[c];
        #pragma unroll 8
        for (int k = 0; k < AA; ++k)
            acc += cfl[a][k] * wl[k * ORIGD + c];
        out1[(size_t)(p0 + a) * ORIGD + c] = acc;
    }
}

extern "C" void kernel_launch(void* const* d_in, const int* in_sizes, int n_in,
                              void* d_out, int out_size, void* d_ws, size_t ws_size,
                              hipStream_t stream) {
    (void)in_sizes; (void)n_in; (void)out_size; (void)ws_size;
    const float* atom_fea  = (const float*)d_in[0];
    const float* nbr_fea   = (const float*)d_in[1];
    const int*   nbr_idx   = (const int*)d_in[2];
    const int*   cidx      = (const int*)d_in[3];
    const float* emb_w     = (const float*)d_in[4];
    const float* fc_full_w = (const float*)d_in[5];
    // d_in[6] fc_full_b: cancelled by batchnorm
    const float* bn1_g = (const float*)d_in[7];
    const float* bn1_b = (const float*)d_in[8];
    const float* bn2_g = (const float*)d_in[9];
    const float* bn2_b = (const float*)d_in[10];
    const float* adj_w = (const float*)d_in[11];
    const float* adj_b = (const float*)d_in[12];
    const float* fc1_w = (const float*)d_in[13];
    const float* fc1_b = (const float*)d_in[14];
    const float* af_w  = (const float*)d_in[15];
    const float* af_b  = (const float*)d_in[16];

    float* out0 = (float*)d_out;
    float* out1 = out0 + (size_t)NB * NPCC * NPCC * 6;

    float* ws = (float*)d_ws;
    float* x      = ws;
    float* y0     = x + (size_t)NATOM * AA;
    float* y1     = y0 + (size_t)NATOM * 128;
    float* summed = y1 + (size_t)NATOM * 128;
    float* logp   = summed + (size_t)NATOM * AA;
    float* stats1 = logp + (size_t)NATOM * 6;          // [NREP][256]
    float* stats2 = stats1 + (size_t)NREP * 256;       // [NREP][128]
    float* sc1    = stats2 + (size_t)NREP * 128;       // [256]
    float* sc2    = sc1 + 256;                         // [128]
    float* endf   = sc2 + 128;
    size_t off = (((size_t)((char*)endf - (char*)d_ws)) + 255) & ~(size_t)255;
    unsigned short* Bt = (unsigned short*)((char*)d_ws + off);   // 128*72 bf16
    unsigned short* Bq = Bt + 128 * 72;                          // 384*72 bf16
    size_t goff = (off + (128 * 72 + 384 * 72) * 2 + 255) & ~(size_t)255;
    uint4* gated = (uint4*)((char*)d_ws + goff);                 // 3125*3072 uint4 = 153.6MB

    const int nstat = NREP * 256 + NREP * 128; // 24576 floats
    k_embed<<<NATOM / 4, 256, 0, stream>>>(atom_fea, emb_w, x);
    k_prepQ<<<108, 256, 0, stream>>>(adj_w, Bq);
    for (int layer = 0; layer < 3; ++layer) {
        const float* W  = fc_full_w + (size_t)layer * 169 * 128;
        const float* W2 = W + 128 * 128;
        k_prep0<<<13, 256, 0, stream>>>(W2, Bt, stats1, nstat);
        k_y01<<<NATOM / 16, 256, 0, stream>>>(x, W, y0, y1);
        k_passA<<<NATOM / 16, 256, 0, stream>>>(y0, y1, nbr_fea, Bt, nbr_idx, stats1, gated);
        k_sc1<<<1, 128, 0, stream>>>(stats1, bn1_g + layer * 128, bn1_b + layer * 128, sc1);
        k_passBs<<<NATOM / 16, 256, 0, stream>>>(gated, sc1, summed, stats2);
        k_sc2<<<1, 64, 0, stream>>>(stats2, bn2_g + layer * 64, bn2_b + layer * 64, sc2);
        k_update<<<(NATOM * AA + 255) / 256, 256, 0, stream>>>(x, summed, sc2);
    }
    k_q<<<(NATOM + 63) / 64, 256, 0, stream>>>(x, cidx, Bq, adj_b, fc1_w, fc1_b, logp);
    k_edge<<<((NB * NPCC * NPCC * 6) / 4 + 255) / 256, 256, 0, stream>>>(logp, out0);
    k_af<<<NATOM / 2, 256, 0, stream>>>(x, cidx, af_w, af_b, out1);
}

// Round 5
// 932.540 us; speedup vs baseline: 1.4105x; 1.0181x over previous
//
#include <hip/hip_runtime.h>
#include <hip/hip_bf16.h>

#define AA 64
#define NBRF 41
#define ORIGD 92
#define NATOM 50000
#define MM 12
#define NB 1000
#define NPCC 50
#define NEDGE (NATOM*MM)
#define NREP 64
constexpr float EPS_BN = 1e-5f;

using bf16 = __hip_bfloat16;
typedef short s16x8 __attribute__((ext_vector_type(8)));
typedef float f32x4 __attribute__((ext_vector_type(4)));

__device__ __forceinline__ float u2f(unsigned short u) {
    union { float f; unsigned int i; } v; v.i = ((unsigned int)u) << 16; return v.f;
}
__device__ __forceinline__ unsigned short f2bu(float f) {
    bf16 h = __float2bfloat16(f);
    return *reinterpret_cast<unsigned short*>(&h);
}
__device__ __forceinline__ float fsigmoid(float x) {
    float e = __expf(-x);
    return __builtin_amdgcn_rcpf(1.f + e);
}
__device__ __forceinline__ float fsoftplus(float x) {
    return fmaxf(x, 0.f) + __logf(1.f + __expf(-fabsf(x)));
}

// global->LDS direct DMA, 16B per lane, lane l lands at lds + l*16
#define GLD16(g, l)                                                              \
    __builtin_amdgcn_global_load_lds(                                            \
        (const __attribute__((address_space(1))) unsigned int*)(g),              \
        (__attribute__((address_space(3))) unsigned int*)(l), 16, 0, 0)

#define WAITV(n)                                                                 \
    do {                                                                         \
        __builtin_amdgcn_sched_barrier(0);                                       \
        asm volatile("s_waitcnt vmcnt(" #n ")" ::: "memory");                    \
        __builtin_amdgcn_sched_barrier(0);                                       \
    } while (0)

// ---------------- merged: zero stats + prep W2^T -> bf16 [128][72] ----------------
__global__ void k_prep0(const float* __restrict__ W2, unsigned short* __restrict__ Bt,
                        float* __restrict__ stats, int nstat) {
    int b = blockIdx.x, t = threadIdx.x;
    if (b == 0) {
        for (int i = t; i < 128 * 72; i += 256) {
            int n = i / 72, kk = i - n * 72;
            float v = (kk < NBRF) ? W2[kk * 128 + n] : 0.f;
            Bt[i] = f2bu(v);
        }
    } else {
        int base = (b - 1) * 2048;
        for (int i = t; i < 2048; i += 256) {
            int idx = base + i;
            if (idx < nstat) stats[idx] = 0.f;
        }
    }
}

// ---------------- prep: adj_w -> Bq bf16 [384 rows(n=o*64+e)][72 (k=d, padded)] ----------------
__global__ void k_prepQ(const float* __restrict__ adjw, unsigned short* __restrict__ Bq) {
    int i = blockIdx.x * 256 + threadIdx.x; // 384*72 = 27648
    if (i >= 384 * 72) return;
    int n = i / 72, k = i - n * 72;
    float v = (k < 64) ? adjw[(n >> 6) * 4096 + k * 64 + (n & 63)] : 0.f;
    Bq[i] = f2bu(v);
}

// ---------------- embed: x = atom_fea @ emb_w  (N,92)@(92,64) ----------------
__global__ __launch_bounds__(256) void k_embed(const float* __restrict__ af,
                                               const float* __restrict__ w,
                                               float* __restrict__ x) {
    __shared__ float wl[ORIGD * AA];
    __shared__ float al[4][ORIGD];
    int t = threadIdx.x;
    for (int i = t; i < ORIGD * AA; i += 256) wl[i] = w[i];
    int n0 = blockIdx.x * 4;
    for (int i = t; i < 4 * ORIGD; i += 256) {
        int a = i / ORIGD, k = i - a * ORIGD;
        al[a][k] = af[(size_t)(n0 + a) * ORIGD + k];
    }
    __syncthreads();
    int c = t & 63, a = t >> 6;
    float acc = 0.f;
    #pragma unroll 4
    for (int k = 0; k < ORIGD; ++k)
        acc += al[a][k] * wl[k * AA + c];
    x[(size_t)(n0 + a) * AA + c] = acc;
}

// ---------------- y0 = x@W[0:64], y1 = x@W[64:128] ----------------
__global__ __launch_bounds__(256) void k_y01(const float* __restrict__ x,
                                             const float* __restrict__ W, // 169x128 layer base
                                             float* __restrict__ y0, float* __restrict__ y1) {
    __shared__ float wl[64 * 128];
    __shared__ float xl[16][AA];
    int t = threadIdx.x;
    int n0 = blockIdx.x * 16;
    for (int i = t; i < 16 * AA; i += 256) {
        int a = i >> 6, k = i & 63;
        xl[a][k] = x[(size_t)(n0 + a) * AA + k];
    }
    int tc = t & 31, sub = t >> 5;
    int c0 = tc * 4;
    for (int half = 0; half < 2; ++half) {
        if (half) __syncthreads();
        const float* Wh = W + (size_t)half * 64 * 128;
        for (int i = t; i < 64 * 128; i += 256) wl[i] = Wh[i];
        __syncthreads();
        float* yout = half ? y1 : y0;
        for (int ah = 0; ah < 2; ++ah) {
            int a = sub + ah * 8;
            float a0=0,a1=0,a2=0,a3=0;
            #pragma unroll 8
            for (int k = 0; k < AA; ++k) {
                float xv = xl[a][k];
                float4 w4 = *reinterpret_cast<const float4*>(&wl[k * 128 + c0]);
                a0 += xv * w4.x; a1 += xv * w4.y; a2 += xv * w4.z; a3 += xv * w4.w;
            }
            float4 r = {a0,a1,a2,a3};
            *reinterpret_cast<float4*>(&yout[(size_t)(n0 + a) * 128 + c0]) = r;
        }
    }
}

// ================= MFMA edge-GEMM pass A =================
// Epilogue v5: wave-private double-buffered DMA staging with counted vmcnt:
// chunk mt+1 loads fly while chunk mt computes. LDS 76KB -> 2 blocks/CU.

#define MFMA_LOOP(acc, Al, Bl, w, ln, quad)                                         \
    _Pragma("unroll")                                                               \
    for (int mt = 0; mt < 3; ++mt) {                                                \
        int mrow = ((w) * 3 + mt) * 16 + (ln);                                      \
        s16x8 a0 = *reinterpret_cast<const s16x8*>(&(Al)[mrow * 72 + (quad) * 8]);  \
        s16x8 a1 = *reinterpret_cast<const s16x8*>(&(Al)[mrow * 72 + (quad) * 8 + 32]); \
        _Pragma("unroll")                                                           \
        for (int nt = 0; nt < 8; ++nt) {                                            \
            int nrow = nt * 16 + (ln);                                              \
            s16x8 b0 = *reinterpret_cast<const s16x8*>(&(Bl)[nrow * 72 + (quad) * 8]);      \
            s16x8 b1 = *reinterpret_cast<const s16x8*>(&(Bl)[nrow * 72 + (quad) * 8 + 32]); \
            acc[mt][nt] = __builtin_amdgcn_mfma_f32_16x16x32_bf16(a0, b0, acc[mt][nt], 0, 0, 0); \
            acc[mt][nt] = __builtin_amdgcn_mfma_f32_16x16x32_bf16(a1, b1, acc[mt][nt], 0, 0, 0); \
        }                                                                           \
    }

#define ISSUE_CHUNK(mt, b)                                                          \
    _Pragma("unroll")                                                               \
    for (int j = 0; j < 8; ++j) {                                                   \
        int m = w * 48 + (mt) * 16 + 2 * j + lh;                                    \
        GLD16(&y1[(size_t)il[m] * 128 + l32 * 4], &y1s[((w * 2 + (b)) * 8 + j) * 264]); \
    }

#define COMPUTE_CHUNK(mt, b)                                                        \
    _Pragma("unroll")                                                               \
    for (int reg = 0; reg < 4; ++reg) {                                             \
        int r2 = quad * 4 + reg;                                                    \
        int m = (w * 3 + (mt)) * 16 + r2;                                           \
        int a = m / MM;                                                             \
        const float* y0rp = &y0s[(a >> 1) * 264 + (a & 1) * 128];                   \
        const float* y1rp = &y1s[((w * 2 + (b)) * 8 + (r2 >> 1)) * 264 + (r2 & 1) * 128]; \
        float r[8];                                                                 \
        _Pragma("unroll")                                                           \
        for (int nt = 0; nt < 8; ++nt) {                                            \
            int n = nt * 16 + ln;                                                   \
            r[nt] = acc[mt][nt][reg] + y0rp[n] + y1rp[n];                           \
            s[nt] += r[nt]; q[nt] += r[nt] * r[nt];                                 \
        }                                                                           \
        uint4 u;                                                                    \
        u.x = (unsigned)f2bu(r[0]) | ((unsigned)f2bu(r[1]) << 16);                  \
        u.y = (unsigned)f2bu(r[2]) | ((unsigned)f2bu(r[3]) << 16);                  \
        u.z = (unsigned)f2bu(r[4]) | ((unsigned)f2bu(r[5]) << 16);                  \
        u.w = (unsigned)f2bu(r[6]) | ((unsigned)f2bu(r[7]) << 16);                  \
        gblk[((mt) * 4 + reg) * 256 + t] = u;                                       \
    }

__global__ __launch_bounds__(256, 2) void k_passA(const float* __restrict__ y0,
                                                  const float* __restrict__ y1,
                                                  const float* __restrict__ nf,
                                                  const unsigned short* __restrict__ Bt,
                                                  const int* __restrict__ nidx,
                                                  float* __restrict__ stats,
                                                  uint4* __restrict__ gated) {
    // Phase 1 alias: Al 192*72 + Bl 128*72 ushort = 46080B.
    // Epilogue alias: y1s 64 pairs x 264 f32 (67584B) + y0s 8 pairs x 264 (8448B) = 76032B.
    __shared__ __attribute__((aligned(16))) unsigned char SMEM[76032];
    __shared__ int il[192];
    unsigned short* Al = reinterpret_cast<unsigned short*>(SMEM);
    unsigned short* Bl = Al + 192 * 72;
    int t = threadIdx.x;
    int n0 = blockIdx.x * 16;
    {
        const float* fg = nf + (size_t)n0 * MM * NBRF;
        #pragma unroll 4
        for (int i = t; i < 192 * NBRF; i += 256) {
            int m = i / NBRF, k = i - m * NBRF;
            Al[m * 72 + k] = f2bu(fg[i]);
        }
        #pragma unroll
        for (int i = t; i < 192 * 23; i += 256) {
            int m = i / 23, k = 41 + (i - m * 23);
            Al[m * 72 + k] = 0;
        }
        #pragma unroll 4
        for (int i = t; i < 128 * 9; i += 256)
            reinterpret_cast<uint4*>(Bl)[i] = reinterpret_cast<const uint4*>(Bt)[i];
        if (t < 192) il[t] = nidx[n0 * MM + t];
    }
    __syncthreads();

    int w = t >> 6, lane = t & 63, ln = lane & 15, quad = lane >> 4;
    f32x4 acc[3][8];
    f32x4 z4 = {0.f, 0.f, 0.f, 0.f};
    for (int i = 0; i < 3; ++i) for (int j = 0; j < 8; ++j) acc[i][j] = z4;
    MFMA_LOOP(acc, Al, Bl, w, ln, quad);
    __syncthreads(); // Al/Bl dead -> alias as staging buffers

    float* y1s = reinterpret_cast<float*>(SMEM);   // 64 pairs x 264
    float* y0s = y1s + 64 * 264;                   // 8 pairs x 264
    int l32 = lane & 31, lh = lane >> 5;
    uint4* gblk = gated + (size_t)blockIdx.x * 3072;
    float s[8] = {0,0,0,0,0,0,0,0}, q[8] = {0,0,0,0,0,0,0,0};

    // prologue: y0 (2) + chunk0 -> buf0 (8) + chunk1 -> buf1 (8); outstanding = 18
    #pragma unroll
    for (int pp = 0; pp < 2; ++pp) {
        int pr = w * 2 + pp;
        GLD16(&y0[(size_t)(n0 + pr * 2 + lh) * 128 + l32 * 4], &y0s[pr * 264]);
    }
    ISSUE_CHUNK(0, 0);
    ISSUE_CHUNK(1, 1);

    WAITV(8);                 // y0 + chunk0 landed; chunk1 (8) in flight
    COMPUTE_CHUNK(0, 0);      // + 4 stores
    __builtin_amdgcn_sched_barrier(0);
    asm volatile("s_waitcnt lgkmcnt(0)" ::: "memory"); // chunk0 LDS reads retired
    __builtin_amdgcn_sched_barrier(0);
    ISSUE_CHUNK(2, 0);        // reuse buf0; flies during chunk1 compute

    WAITV(12);                // chunk1 landed (S0 4 + L2 8 may remain)
    COMPUTE_CHUNK(1, 1);

    WAITV(4);                 // chunk2 landed (S1 4 may remain)
    COMPUTE_CHUNK(2, 0);

    #pragma unroll
    for (int nt = 0; nt < 8; ++nt) {
        s[nt] += __shfl_xor(s[nt], 16); s[nt] += __shfl_xor(s[nt], 32);
        q[nt] += __shfl_xor(q[nt], 16); q[nt] += __shfl_xor(q[nt], 32);
    }
    __syncthreads(); // staging buffers dead -> alias as red
    float* red = reinterpret_cast<float*>(SMEM); // [4 waves][8 nt][16 ln][2]
    if (quad == 0) {
        #pragma unroll
        for (int nt = 0; nt < 8; ++nt) {
            red[((w * 8 + nt) * 16 + ln) * 2 + 0] = s[nt];
            red[((w * 8 + nt) * 16 + ln) * 2 + 1] = q[nt];
        }
    }
    __syncthreads();
    {
        int c = t >> 1, j = t & 1; // c in 0..127
        float v = 0.f;
        #pragma unroll
        for (int w2 = 0; w2 < 4; ++w2)
            v += red[((w2 * 8 + (c >> 4)) * 16 + (c & 15)) * 2 + j];
        int rep = (blockIdx.x & (NREP - 1)) << 8;
        atomicAdd(&stats[rep + j * 128 + c], v);
    }
}

// ---------------- bn1 fold (sums NREP replicas) ----------------
__global__ void k_sc1(const float* __restrict__ stats, const float* __restrict__ g,
                      const float* __restrict__ b, float* __restrict__ sc) {
    int c = threadIdx.x; // 128
    float s = 0.f, q = 0.f;
    for (int r = 0; r < NREP; ++r) {
        s += stats[r * 256 + c];
        q += stats[r * 256 + 128 + c];
    }
    float cnt = (float)NEDGE;
    float mean = s / cnt;
    float var = q / cnt - mean * mean;
    float inv = rsqrtf(var + EPS_BN);
    float scale = g[c] * inv;
    sc[c] = scale;
    sc[128 + c] = b[c] - mean * scale;
}

// ---------------- pass B (streaming): read gated, BN1+act, sum over neighbors ----------------
__global__ __launch_bounds__(256) void k_passBs(const uint4* __restrict__ gated,
                                                const float* __restrict__ sc,
                                                float* __restrict__ summed,
                                                float* __restrict__ stats2) {
    __shared__ unsigned short P[192 * 66]; // 25344B
    __shared__ float sred[512];
    int t = threadIdx.x;
    int n0 = blockIdx.x * 16;
    int w = t >> 6, lane = t & 63, ln = lane & 15, quad = lane >> 4;
    float scF[4], shF[4], scC[4], shC[4];
    #pragma unroll
    for (int nt = 0; nt < 4; ++nt) {
        int cc = nt * 16 + ln;
        scF[nt] = sc[cc];      shF[nt] = sc[128 + cc];
        scC[nt] = sc[64 + cc]; shC[nt] = sc[192 + cc];
    }
    const uint4* gblk = gated + (size_t)blockIdx.x * 3072;
    #pragma unroll
    for (int mt = 0; mt < 3; ++mt) {
        #pragma unroll
        for (int reg = 0; reg < 4; ++reg) {
            uint4 u = gblk[(mt * 4 + reg) * 256 + t];
            int m = (w * 3 + mt) * 16 + quad * 4 + reg;
            unsigned uu[4] = {u.x, u.y, u.z, u.w};
            #pragma unroll
            for (int nt = 0; nt < 4; ++nt) {
                float rfv = u2f((unsigned short)((nt & 1) ? (uu[nt >> 1] >> 16) : (uu[nt >> 1] & 0xffff)));
                float rcv = u2f((unsigned short)((nt & 1) ? (uu[2 + (nt >> 1)] >> 16) : (uu[2 + (nt >> 1)] & 0xffff)));
                float rf = rfv * scF[nt] + shF[nt];
                float rc = rcv * scC[nt] + shC[nt];
                P[m * 66 + nt * 16 + ln] = f2bu(fsigmoid(rf) * fsoftplus(rc));
            }
        }
    }
    __syncthreads();
    int cc = t & 63, who = t >> 6;
    float sA = 0.f, qA = 0.f;
    #pragma unroll
    for (int k2 = 0; k2 < 4; ++k2) {
        int a = who + k2 * 4;
        float v = 0.f;
        #pragma unroll
        for (int j = 0; j < 12; ++j) v += u2f(P[(a * 12 + j) * 66 + cc]);
        summed[(size_t)(n0 + a) * AA + cc] = v;
        sA += v; qA += v * v;
    }
    sred[who * 64 + cc] = sA;
    sred[256 + who * 64 + cc] = qA;
    __syncthreads();
    if (t < 64) {
        float s4 = sred[t] + sred[64 + t] + sred[128 + t] + sred[192 + t];
        float q4 = sred[256 + t] + sred[320 + t] + sred[384 + t] + sred[448 + t];
        int rep = (blockIdx.x & (NREP - 1)) << 7; // replicas of [128]
        atomicAdd(&stats2[rep + t], s4);
        atomicAdd(&stats2[rep + 64 + t], q4);
    }
}

// ---------------- bn2 fold (sums NREP replicas) ----------------
__global__ void k_sc2(const float* __restrict__ stats2, const float* __restrict__ g,
                      const float* __restrict__ b, float* __restrict__ sc2) {
    int c = threadIdx.x; // 64
    float s = 0.f, q = 0.f;
    for (int r = 0; r < NREP; ++r) {
        s += stats2[r * 128 + c];
        q += stats2[r * 128 + 64 + c];
    }
    float cnt = (float)NATOM;
    float mean = s / cnt;
    float var = q / cnt - mean * mean;
    float inv = rsqrtf(var + EPS_BN);
    float scale = g[c] * inv;
    sc2[c] = scale;
    sc2[64 + c] = b[c] - mean * scale;
}

// ---------------- x = softplus(x + bn2(summed)) ----------------
__global__ void k_update(float* __restrict__ x, const float* __restrict__ summed,
                         const float* __restrict__ sc2) {
    int i = blockIdx.x * blockDim.x + threadIdx.x;
    if (i < NATOM * AA) {
        int c = i & 63;
        float s = summed[i] * sc2[c] + sc2[64 + c];
        x[i] = fsoftplus(x[i] + s);
    }
}

// ---------------- bilinear head via MFMA ----------------
__global__ __launch_bounds__(256) void k_q(const float* __restrict__ x, const int* __restrict__ cidx,
                                           const unsigned short* __restrict__ Bq, // 384x72 bf16
                                           const float* __restrict__ adjb,
                                           const float* __restrict__ fc1w,
                                           const float* __restrict__ fc1b,
                                           float* __restrict__ logp) {
    __shared__ __attribute__((aligned(16))) unsigned short Aq[64 * 72];  // 9216B
    __shared__ __attribute__((aligned(16))) unsigned short Bl[384 * 72]; // 55296B
    __shared__ float qv[64][6];
    int t = threadIdx.x;
    int p0 = blockIdx.x * 64;
    for (int i = t; i < 64 * 72; i += 256) {
        int a = i / 72, k = i - a * 72;
        int ga = p0 + a;
        float v = (k < 64 && ga < NATOM) ? x[(size_t)cidx[ga < NATOM ? ga : 0] * AA + k] : 0.f;
        Aq[i] = f2bu(v);
    }
    for (int i = t; i < 3456; i += 256)
        reinterpret_cast<uint4*>(Bl)[i] = reinterpret_cast<const uint4*>(Bq)[i];
    __syncthreads();

    int w = t >> 6, lane = t & 63, ln = lane & 15, quad = lane >> 4;
    f32x4 acc[24];
    f32x4 z4 = {0.f, 0.f, 0.f, 0.f};
    #pragma unroll
    for (int i = 0; i < 24; ++i) acc[i] = z4;
    {
        int mrow = w * 16 + ln;
        s16x8 a0 = *reinterpret_cast<const s16x8*>(&Aq[mrow * 72 + quad * 8]);
        s16x8 a1 = *reinterpret_cast<const s16x8*>(&Aq[mrow * 72 + quad * 8 + 32]);
        #pragma unroll
        for (int nt = 0; nt < 24; ++nt) {
            int nrow = nt * 16 + ln;
            s16x8 b0 = *reinterpret_cast<const s16x8*>(&Bl[nrow * 72 + quad * 8]);
            s16x8 b1 = *reinterpret_cast<const s16x8*>(&Bl[nrow * 72 + quad * 8 + 32]);
            acc[nt] = __builtin_amdgcn_mfma_f32_16x16x32_bf16(a0, b0, acc[nt], 0, 0, 0);
            acc[nt] = __builtin_amdgcn_mfma_f32_16x16x32_bf16(a1, b1, acc[nt], 0, 0, 0);
        }
    }
    float cfv[4][4];
    #pragma unroll
    for (int reg = 0; reg < 4; ++reg) {
        int ga = p0 + w * 16 + quad * 4 + reg;
        const float* xr = x + (size_t)cidx[ga < NATOM ? ga : 0] * AA;
        #pragma unroll
        for (int et = 0; et < 4; ++et)
            cfv[reg][et] = (ga < NATOM) ? xr[et * 16 + ln] : 0.f;
    }
    float bo[6];
    #pragma unroll
    for (int o = 0; o < 6; ++o) bo[o] = adjb[o];
    #pragma unroll
    for (int reg = 0; reg < 4; ++reg) {
        #pragma unroll
        for (int o = 0; o < 6; ++o) {
            float p = 0.f;
            #pragma unroll
            for (int et = 0; et < 4; ++et)
                p += acc[o * 4 + et][reg] * cfv[reg][et];
            p += __shfl_xor(p, 1); p += __shfl_xor(p, 2);
            p += __shfl_xor(p, 4); p += __shfl_xor(p, 8);
            if (ln == 0) qv[w * 16 + quad * 4 + reg][o] = p + bo[o];
        }
    }
    __syncthreads();
    if (t < 64) {
        int ga = p0 + t;
        if (ga < NATOM) {
            float q2[6];
            float mx = -1e30f;
            #pragma unroll
            for (int o2 = 0; o2 < 6; ++o2) {
                float acc2 = fc1b[o2];
                #pragma unroll
                for (int o = 0; o < 6; ++o) acc2 += qv[t][o] * fc1w[o * 6 + o2];
                q2[o2] = acc2; mx = fmaxf(mx, acc2);
            }
            float se = 0.f;
            #pragma unroll
            for (int o2 = 0; o2 < 6; ++o2) se += __expf(q2[o2] - mx);
            float lse = mx + __logf(se);
            #pragma unroll
            for (int o2 = 0; o2 < 6; ++o2) logp[(size_t)ga * 6 + o2] = q2[o2] - lse;
        }
    }
}

// ---------------- edge_prob broadcast write ----------------
__global__ void k_edge(const float* __restrict__ logp, float* __restrict__ out0) {
    int i4 = blockIdx.x * blockDim.x + threadIdx.x;
    if (i4 >= (NB * NPCC * NPCC * 6) / 4) return;
    int e = i4 * 4;
    int b = e / (NPCC * NPCC * 6);
    int rr = e - b * (NPCC * NPCC * 6);
    const float* lb = &logp[(size_t)b * NPCC * 6];
    float4 v;
    int r0 = rr % 300;       v.x = lb[r0];
    int r1 = (rr + 1) % 300; v.y = lb[r1];
    int r2 = (rr + 2) % 300; v.z = lb[r2];
    int r3 = (rr + 3) % 300; v.w = lb[r3];
    *reinterpret_cast<float4*>(&out0[e]) = v;
}

// ---------------- atom_feature = cf @ af_w + af_b (16 atoms/block) ----------------
__global__ __launch_bounds__(256) void k_af(const float* __restrict__ x, const int* __restrict__ cidx,
                                            const float* __restrict__ afw,
                                            const float* __restrict__ afb,
                                            float* __restrict__ out1) {
    __shared__ float wl[AA * ORIGD];   // 23552B
    __shared__ float cfl[16][AA];      // 4096B
    __shared__ float bl[ORIGD];
    int t = threadIdx.x;
    for (int i = t; i < AA * ORIGD; i += 256) wl[i] = afw[i];
    if (t < ORIGD) bl[t] = afb[t];
    int p0 = blockIdx.x * 16;
    for (int i = t; i < 16 * AA; i += 256) {
        int a = i >> 6, e = i & 63;
        cfl[a][e] = x[(size_t)cidx[p0 + a] * AA + e];
    }
    __syncthreads();
    for (int i = t; i < 16 * ORIGD; i += 256) {
        int a = i / ORIGD, c = i - a * ORIGD;
        float acc = bl[c];
        #pragma unroll 8
        for (int k = 0; k < AA; ++k)
            acc += cfl[a][k] * wl[k * ORIGD + c];
        out1[(size_t)(p0 + a) * ORIGD + c] = acc;
    }
}

extern "C" void kernel_launch(void* const* d_in, const int* in_sizes, int n_in,
                              void* d_out, int out_size, void* d_ws, size_t ws_size,
                              hipStream_t stream) {
    (void)in_sizes; (void)n_in; (void)out_size; (void)ws_size;
    const float* atom_fea  = (const float*)d_in[0];
    const float* nbr_fea   = (const float*)d_in[1];
    const int*   nbr_idx   = (const int*)d_in[2];
    const int*   cidx      = (const int*)d_in[3];
    const float* emb_w     = (const float*)d_in[4];
    const float* fc_full_w = (const float*)d_in[5];
    // d_in[6] fc_full_b: cancelled by batchnorm
    const float* bn1_g = (const float*)d_in[7];
    const float* bn1_b = (const float*)d_in[8];
    const float* bn2_g = (const float*)d_in[9];
    const float* bn2_b = (const float*)d_in[10];
    const float* adj_w = (const float*)d_in[11];
    const float* adj_b = (const float*)d_in[12];
    const float* fc1_w = (const float*)d_in[13];
    const float* fc1_b = (const float*)d_in[14];
    const float* af_w  = (const float*)d_in[15];
    const float* af_b  = (const float*)d_in[16];

    float* out0 = (float*)d_out;
    float* out1 = out0 + (size_t)NB * NPCC * NPCC * 6;

    float* ws = (float*)d_ws;
    float* x      = ws;
    float* y0     = x + (size_t)NATOM * AA;
    float* y1     = y0 + (size_t)NATOM * 128;
    float* summed = y1 + (size_t)NATOM * 128;
    float* logp   = summed + (size_t)NATOM * AA;
    float* stats1 = logp + (size_t)NATOM * 6;          // [NREP][256]
    float* stats2 = stats1 + (size_t)NREP * 256;       // [NREP][128]
    float* sc1    = stats2 + (size_t)NREP * 128;       // [256]
    float* sc2    = sc1 + 256;                         // [128]
    float* endf   = sc2 + 128;
    size_t off = (((size_t)((char*)endf - (char*)d_ws)) + 255) & ~(size_t)255;
    unsigned short* Bt = (unsigned short*)((char*)d_ws + off);   // 128*72 bf16
    unsigned short* Bq = Bt + 128 * 72;                          // 384*72 bf16
    size_t goff = (off + (128 * 72 + 384 * 72) * 2 + 255) & ~(size_t)255;
    uint4* gated = (uint4*)((char*)d_ws + goff);                 // 3125*3072 uint4 = 153.6MB

    const int nstat = NREP * 256 + NREP * 128; // 24576 floats
    k_embed<<<NATOM / 4, 256, 0, stream>>>(atom_fea, emb_w, x);
    k_prepQ<<<108, 256, 0, stream>>>(adj_w, Bq);
    for (int layer = 0; layer < 3; ++layer) {
        const float* W  = fc_full_w + (size_t)layer * 169 * 128;
        const float* W2 = W + 128 * 128;
        k_prep0<<<13, 256, 0, stream>>>(W2, Bt, stats1, nstat);
        k_y01<<<NATOM / 16, 256, 0, stream>>>(x, W, y0, y1);
        k_passA<<<NATOM / 16, 256, 0, stream>>>(y0, y1, nbr_fea, Bt, nbr_idx, stats1, gated);
        k_sc1<<<1, 128, 0, stream>>>(stats1, bn1_g + layer * 128, bn1_b + layer * 128, sc1);
        k_passBs<<<NATOM / 16, 256, 0, stream>>>(gated, sc1, summed, stats2);
        k_sc2<<<1, 64, 0, stream>>>(stats2, bn2_g + layer * 64, bn2_b + layer * 64, sc2);
        k_update<<<(NATOM * AA + 255) / 256, 256, 0, stream>>>(x, summed, sc2);
    }
    k_q<<<(NATOM + 63) / 64, 256, 0, stream>>>(x, cidx, Bq, adj_b, fc1_w, fc1_b, logp);
    k_edge<<<((NB * NPCC * NPCC * 6) / 4 + 255) / 256, 256, 0, stream>>>(logp, out0);
    k_af<<<NATOM / 16, 256, 0, stream>>>(x, cidx, af_w, af_b, out1);
}

// Round 7
// 759.974 us; speedup vs baseline: 1.7308x; 1.2271x over previous
//
#include <hip/hip_runtime.h>
#include <hip/hip_bf16.h>

#define AA 64
#define NBRF 41
#define ORIGD 92
#define NATOM 50000
#define MM 12
#define NB 1000
#define NPCC 50
#define NEDGE (NATOM*MM)
#define NREP 64
constexpr float EPS_BN = 1e-5f;

using bf16 = __hip_bfloat16;
typedef short s16x8 __attribute__((ext_vector_type(8)));
typedef float f32x4 __attribute__((ext_vector_type(4)));

__device__ __forceinline__ float u2f(unsigned short u) {
    union { float f; unsigned int i; } v; v.i = ((unsigned int)u) << 16; return v.f;
}
__device__ __forceinline__ unsigned short f2bu(float f) {
    bf16 h = __float2bfloat16(f);
    return *reinterpret_cast<unsigned short*>(&h);
}
__device__ __forceinline__ float fsigmoid(float x) {
    float e = __expf(-x);
    return __builtin_amdgcn_rcpf(1.f + e);
}
__device__ __forceinline__ float fsoftplus(float x) {
    return fmaxf(x, 0.f) + __logf(1.f + __expf(-fabsf(x)));
}

// global->LDS direct DMA, 16B per lane, lane l lands at lds + l*16.
// NOTE: the GLOBAL source address is PER-LANE — caller must include the
// lane offset in g (R5 bug: uniform source = 64 copies of the same 16B).
#define GLD16(g, l)                                                              \
    __builtin_amdgcn_global_load_lds(                                            \
        (const __attribute__((address_space(1))) unsigned int*)(g),              \
        (__attribute__((address_space(3))) unsigned int*)(l), 16, 0, 0)

// ---------------- merged: prep Wt (3 transposed bf16 W parts) + zero stats ----------------
// Wt layout: part p in [0,3): [128 rows(n)][72 cols(k)] bf16.
//   p=0: W2t (nbr_fea weights, k<41), p=1: W1t (x_nbr, k<64), p=2: W0t (x_self, k<64)
__global__ void k_prep0(const float* __restrict__ W, unsigned short* __restrict__ Wt,
                        float* __restrict__ stats, int nstat) {
    int b = blockIdx.x, t = threadIdx.x;
    if (b < 3) {
        for (int i = t; i < 9216; i += 256) {
            int n = i / 72, k = i - n * 72;
            float v = 0.f;
            if (b == 0)      { if (k < NBRF) v = W[(128 + k) * 128 + n]; }
            else if (b == 1) { if (k < 64)   v = W[(64 + k) * 128 + n]; }
            else             { if (k < 64)   v = W[k * 128 + n]; }
            Wt[b * 9216 + i] = f2bu(v);
        }
    } else {
        int base = (b - 3) * 2048;
        for (int i = t; i < 2048; i += 256) {
            int idx = base + i;
            if (idx < nstat) stats[idx] = 0.f;
        }
    }
}

// ---------------- prep: adj_w -> Bq bf16 [384 rows(n=o*64+e)][72 (k=d, padded)] ----------------
__global__ void k_prepQ(const float* __restrict__ adjw, unsigned short* __restrict__ Bq) {
    int i = blockIdx.x * 256 + threadIdx.x; // 384*72 = 27648
    if (i >= 384 * 72) return;
    int n = i / 72, k = i - n * 72;
    float v = (k < 64) ? adjw[(n >> 6) * 4096 + k * 64 + (n & 63)] : 0.f;
    Bq[i] = f2bu(v);
}

// ---------------- embed: x = atom_fea @ emb_w  (N,92)@(92,64); also writes bf16 copy ----------------
__global__ __launch_bounds__(256) void k_embed(const float* __restrict__ af,
                                               const float* __restrict__ w,
                                               float* __restrict__ x,
                                               unsigned short* __restrict__ xb) {
    __shared__ float wl[ORIGD * AA];
    __shared__ float al[4][ORIGD];
    int t = threadIdx.x;
    for (int i = t; i < ORIGD * AA; i += 256) wl[i] = w[i];
    int n0 = blockIdx.x * 4;
    for (int i = t; i < 4 * ORIGD; i += 256) {
        int a = i / ORIGD, k = i - a * ORIGD;
        al[a][k] = af[(size_t)(n0 + a) * ORIGD + k];
    }
    __syncthreads();
    int c = t & 63, a = t >> 6;
    float acc = 0.f;
    #pragma unroll 4
    for (int k = 0; k < ORIGD; ++k)
        acc += al[a][k] * wl[k * AA + c];
    size_t idx = (size_t)(n0 + a) * AA + c;
    x[idx] = acc;
    xb[idx] = f2bu(acc);
}

// ================= fused MFMA edge-GEMM pass A (v6.1) =================
// Per block: 16 atoms -> 192 edges.
// gated = nbr_fea@W2 + x_nbr@W1 + x_self@W0, all via bf16 MFMA, 3 accumulating
// K=64 phases sharing one accumulator. No y0/y1 buffers, no f32 gather.
// x gathered as bf16 rows (128B) via global_load_lds with pre-swizzled source;
// swizzled LDS read keeps ds_read_b128 at the bank minimum.

#define MFMA_PH1(acc)                                                               \
    _Pragma("unroll")                                                               \
    for (int mt = 0; mt < 3; ++mt) {                                                \
        int mrow = w * 48 + mt * 16 + ln;                                           \
        s16x8 a0 = *reinterpret_cast<const s16x8*>(&Al[mrow * 72 + quad * 8]);      \
        s16x8 a1 = *reinterpret_cast<const s16x8*>(&Al[mrow * 72 + quad * 8 + 32]); \
        _Pragma("unroll")                                                           \
        for (int nt = 0; nt < 8; ++nt) {                                            \
            int nrow = nt * 16 + ln;                                                \
            s16x8 b0 = *reinterpret_cast<const s16x8*>(&Bl[nrow * 72 + quad * 8]);  \
            s16x8 b1 = *reinterpret_cast<const s16x8*>(&Bl[nrow * 72 + quad * 8 + 32]); \
            acc[mt][nt] = __builtin_amdgcn_mfma_f32_16x16x32_bf16(a0, b0, acc[mt][nt], 0, 0, 0); \
            acc[mt][nt] = __builtin_amdgcn_mfma_f32_16x16x32_bf16(a1, b1, acc[mt][nt], 0, 0, 0); \
        }                                                                           \
    }

__global__ __launch_bounds__(256, 2) void k_passA(const unsigned short* __restrict__ xb,
                                                  const float* __restrict__ nf,
                                                  const unsigned short* __restrict__ Wt,
                                                  const int* __restrict__ nidx,
                                                  float* __restrict__ stats,
                                                  uint4* __restrict__ gated) {
    // Al 192*72 (27648B) | Ax 192*64 swz (24576B) | As 16*64 swz (2048B) | Bl 128*72 (18432B)
    __shared__ __attribute__((aligned(16))) unsigned char SMEM[72704];
    unsigned short* Al = reinterpret_cast<unsigned short*>(SMEM);
    unsigned short* Ax = Al + 192 * 72;
    unsigned short* As = Ax + 192 * 64;
    unsigned short* Bl = As + 16 * 64;
    int t = threadIdx.x;
    int n0 = blockIdx.x * 16;
    int w = t >> 6, lane = t & 63, ln = lane & 15, quad = lane >> 4;

    // ---- stage Al: nbr_fea f32 -> bf16, 72-stride, cols 41..63 zeroed ----
    {
        const float* fg = nf + (size_t)n0 * MM * NBRF;
        #pragma unroll 4
        for (int i = t; i < 192 * NBRF; i += 256) {
            int m = i / NBRF, k = i - m * NBRF;
            Al[m * 72 + k] = f2bu(fg[i]);
        }
        #pragma unroll
        for (int i = t; i < 192 * 23; i += 256) {
            int m = i / 23, k = 41 + (i - m * 23);
            Al[m * 72 + k] = 0;
        }
    }
    // ---- Bl <- Wt part0 (W2t), per-wave DMA chunks (per-lane source!) ----
    for (int c = w; c < 18; c += 4)
        GLD16(Wt + c * 512 + lane * 8, (char*)Bl + c * 1024);
    // ---- neighbor indices for this wave's Ax rows (VGPR, 8-lane broadcast) ----
    const int* nb = nidx + n0 * MM;
    int idxv[6];
    #pragma unroll
    for (int c = 0; c < 6; ++c) idxv[c] = nb[w * 48 + c * 8 + (lane >> 3)];
    int sl = ((lane & 7) ^ ((lane >> 3) & 7)) * 8;  // pre-swizzled source slot (bf16 elems)
    __syncthreads();

    // ---- issue gathered-x DMA; flies under MFMA phase 1 ----
    #pragma unroll
    for (int c = 0; c < 6; ++c)
        GLD16(xb + (size_t)idxv[c] * 64 + sl, (char*)Ax + (w * 48 + c * 8) * 128);
    if (w == 3) {
        GLD16(xb + (size_t)(n0 + (lane >> 3)) * 64 + sl, (char*)As);
        GLD16(xb + (size_t)(n0 + 8 + (lane >> 3)) * 64 + sl, (char*)As + 1024);
    }

    f32x4 acc[3][8];
    f32x4 z4 = {0.f, 0.f, 0.f, 0.f};
    for (int i = 0; i < 3; ++i) for (int j = 0; j < 8; ++j) acc[i][j] = z4;

    // ---- phase 1: nbr_fea @ W2 ----
    MFMA_PH1(acc);
    __syncthreads();   // Bl readers done; barrier drains each wave's own DMA (Ax/As ready after)
    for (int c = w; c < 18; c += 4)
        GLD16(Wt + 9216 + c * 512 + lane * 8, (char*)Bl + c * 1024);
    __syncthreads();

    // ---- phase 2: x_nbr @ W1 (swizzled-64 A) ----
    {
        int sw0 = (quad ^ (ln & 7)) * 8, sw1 = ((quad + 4) ^ (ln & 7)) * 8;
        #pragma unroll
        for (int mt = 0; mt < 3; ++mt) {
            int mrow = w * 48 + mt * 16 + ln;
            s16x8 a0 = *reinterpret_cast<const s16x8*>(&Ax[mrow * 64 + sw0]);
            s16x8 a1 = *reinterpret_cast<const s16x8*>(&Ax[mrow * 64 + sw1]);
            #pragma unroll
            for (int nt = 0; nt < 8; ++nt) {
                int nrow = nt * 16 + ln;
                s16x8 b0 = *reinterpret_cast<const s16x8*>(&Bl[nrow * 72 + quad * 8]);
                s16x8 b1 = *reinterpret_cast<const s16x8*>(&Bl[nrow * 72 + quad * 8 + 32]);
                acc[mt][nt] = __builtin_amdgcn_mfma_f32_16x16x32_bf16(a0, b0, acc[mt][nt], 0, 0, 0);
                acc[mt][nt] = __builtin_amdgcn_mfma_f32_16x16x32_bf16(a1, b1, acc[mt][nt], 0, 0, 0);
            }
        }
    }
    __syncthreads();
    for (int c = w; c < 18; c += 4)
        GLD16(Wt + 2 * 9216 + c * 512 + lane * 8, (char*)Bl + c * 1024);
    __syncthreads();

    // ---- phase 3: x_self @ W0 (16 swizzled rows, row = atom = edge/12) ----
    #pragma unroll
    for (int mt = 0; mt < 3; ++mt) {
        int mrow = w * 48 + mt * 16 + ln;
        int atom = mrow / 12;
        int s0 = (quad ^ (atom & 7)) * 8, s1 = ((quad + 4) ^ (atom & 7)) * 8;
        s16x8 a0 = *reinterpret_cast<const s16x8*>(&As[atom * 64 + s0]);
        s16x8 a1 = *reinterpret_cast<const s16x8*>(&As[atom * 64 + s1]);
        #pragma unroll
        for (int nt = 0; nt < 8; ++nt) {
            int nrow = nt * 16 + ln;
            s16x8 b0 = *reinterpret_cast<const s16x8*>(&Bl[nrow * 72 + quad * 8]);
            s16x8 b1 = *reinterpret_cast<const s16x8*>(&Bl[nrow * 72 + quad * 8 + 32]);
            acc[mt][nt] = __builtin_amdgcn_mfma_f32_16x16x32_bf16(a0, b0, acc[mt][nt], 0, 0, 0);
            acc[mt][nt] = __builtin_amdgcn_mfma_f32_16x16x32_bf16(a1, b1, acc[mt][nt], 0, 0, 0);
        }
    }

    // ---- epilogue: BN1 stats + bf16 pack + coalesced store ----
    uint4* gblk = gated + (size_t)blockIdx.x * 3072;
    float s[8] = {0,0,0,0,0,0,0,0}, q[8] = {0,0,0,0,0,0,0,0};
    #pragma unroll
    for (int mt = 0; mt < 3; ++mt) {
        #pragma unroll
        for (int reg = 0; reg < 4; ++reg) {
            float r[8];
            #pragma unroll
            for (int nt = 0; nt < 8; ++nt) {
                r[nt] = acc[mt][nt][reg];
                s[nt] += r[nt]; q[nt] += r[nt] * r[nt];
            }
            uint4 u;
            u.x = (unsigned)f2bu(r[0]) | ((unsigned)f2bu(r[1]) << 16);
            u.y = (unsigned)f2bu(r[2]) | ((unsigned)f2bu(r[3]) << 16);
            u.z = (unsigned)f2bu(r[4]) | ((unsigned)f2bu(r[5]) << 16);
            u.w = (unsigned)f2bu(r[6]) | ((unsigned)f2bu(r[7]) << 16);
            gblk[(mt * 4 + reg) * 256 + t] = u; // coalesced per (mt,reg)
        }
    }
    #pragma unroll
    for (int nt = 0; nt < 8; ++nt) {
        s[nt] += __shfl_xor(s[nt], 16); s[nt] += __shfl_xor(s[nt], 32);
        q[nt] += __shfl_xor(q[nt], 16); q[nt] += __shfl_xor(q[nt], 32);
    }
    __syncthreads(); // staging regions dead -> alias as red
    float* red = reinterpret_cast<float*>(SMEM); // [4 waves][8 nt][16 ln][2]
    if (quad == 0) {
        #pragma unroll
        for (int nt = 0; nt < 8; ++nt) {
            red[((w * 8 + nt) * 16 + ln) * 2 + 0] = s[nt];
            red[((w * 8 + nt) * 16 + ln) * 2 + 1] = q[nt];
        }
    }
    __syncthreads();
    {
        int c = t >> 1, j = t & 1; // c in 0..127
        float v = 0.f;
        #pragma unroll
        for (int w2 = 0; w2 < 4; ++w2)
            v += red[((w2 * 8 + (c >> 4)) * 16 + (c & 15)) * 2 + j];
        int rep = (blockIdx.x & (NREP - 1)) << 8;
        atomicAdd(&stats[rep + j * 128 + c], v);
    }
}

// ---------------- bn1 fold (sums NREP replicas) ----------------
__global__ void k_sc1(const float* __restrict__ stats, const float* __restrict__ g,
                      const float* __restrict__ b, float* __restrict__ sc) {
    int c = threadIdx.x; // 128
    float s = 0.f, q = 0.f;
    for (int r = 0; r < NREP; ++r) {
        s += stats[r * 256 + c];
        q += stats[r * 256 + 128 + c];
    }
    float cnt = (float)NEDGE;
    float mean = s / cnt;
    float var = q / cnt - mean * mean;
    float inv = rsqrtf(var + EPS_BN);
    float scale = g[c] * inv;
    sc[c] = scale;
    sc[128 + c] = b[c] - mean * scale;
}

// ---------------- pass B (streaming): read gated, BN1+act, sum over neighbors ----------------
__global__ __launch_bounds__(256) void k_passBs(const uint4* __restrict__ gated,
                                                const float* __restrict__ sc,
                                                float* __restrict__ summed,
                                                float* __restrict__ stats2) {
    __shared__ unsigned short P[192 * 66]; // 25344B
    __shared__ float sred[512];
    int t = threadIdx.x;
    int n0 = blockIdx.x * 16;
    int w = t >> 6, lane = t & 63, ln = lane & 15, quad = lane >> 4;
    float scF[4], shF[4], scC[4], shC[4];
    #pragma unroll
    for (int nt = 0; nt < 4; ++nt) {
        int cc = nt * 16 + ln;
        scF[nt] = sc[cc];      shF[nt] = sc[128 + cc];
        scC[nt] = sc[64 + cc]; shC[nt] = sc[192 + cc];
    }
    const uint4* gblk = gated + (size_t)blockIdx.x * 3072;
    #pragma unroll
    for (int mt = 0; mt < 3; ++mt) {
        #pragma unroll
        for (int reg = 0; reg < 4; ++reg) {
            uint4 u = gblk[(mt * 4 + reg) * 256 + t];
            int m = (w * 3 + mt) * 16 + quad * 4 + reg;
            unsigned uu[4] = {u.x, u.y, u.z, u.w};
            #pragma unroll
            for (int nt = 0; nt < 4; ++nt) {
                float rfv = u2f((unsigned short)((nt & 1) ? (uu[nt >> 1] >> 16) : (uu[nt >> 1] & 0xffff)));
                float rcv = u2f((unsigned short)((nt & 1) ? (uu[2 + (nt >> 1)] >> 16) : (uu[2 + (nt >> 1)] & 0xffff)));
                float rf = rfv * scF[nt] + shF[nt];
                float rc = rcv * scC[nt] + shC[nt];
                P[m * 66 + nt * 16 + ln] = f2bu(fsigmoid(rf) * fsoftplus(rc));
            }
        }
    }
    __syncthreads();
    int cc = t & 63, who = t >> 6;
    float sA = 0.f, qA = 0.f;
    #pragma unroll
    for (int k2 = 0; k2 < 4; ++k2) {
        int a = who + k2 * 4;
        float v = 0.f;
        #pragma unroll
        for (int j = 0; j < 12; ++j) v += u2f(P[(a * 12 + j) * 66 + cc]);
        summed[(size_t)(n0 + a) * AA + cc] = v;
        sA += v; qA += v * v;
    }
    sred[who * 64 + cc] = sA;
    sred[256 + who * 64 + cc] = qA;
    __syncthreads();
    if (t < 64) {
        float s4 = sred[t] + sred[64 + t] + sred[128 + t] + sred[192 + t];
        float q4 = sred[256 + t] + sred[320 + t] + sred[384 + t] + sred[448 + t];
        int rep = (blockIdx.x & (NREP - 1)) << 7; // replicas of [128]
        atomicAdd(&stats2[rep + t], s4);
        atomicAdd(&stats2[rep + 64 + t], q4);
    }
}

// ---------------- bn2 fold (sums NREP replicas) ----------------
__global__ void k_sc2(const float* __restrict__ stats2, const float* __restrict__ g,
                      const float* __restrict__ b, float* __restrict__ sc2) {
    int c = threadIdx.x; // 64
    float s = 0.f, q = 0.f;
    for (int r = 0; r < NREP; ++r) {
        s += stats2[r * 128 + c];
        q += stats2[r * 128 + 64 + c];
    }
    float cnt = (float)NATOM;
    float mean = s / cnt;
    float var = q / cnt - mean * mean;
    float inv = rsqrtf(var + EPS_BN);
    float scale = g[c] * inv;
    sc2[c] = scale;
    sc2[64 + c] = b[c] - mean * scale;
}

// ---------------- x = softplus(x + bn2(summed)); also refresh bf16 copy ----------------
__global__ void k_update(float* __restrict__ x, const float* __restrict__ summed,
                         const float* __restrict__ sc2, unsigned short* __restrict__ xb) {
    int i = blockIdx.x * blockDim.x + threadIdx.x;
    if (i < NATOM * AA) {
        int c = i & 63;
        float s = summed[i] * sc2[c] + sc2[64 + c];
        float v = fsoftplus(x[i] + s);
        x[i] = v;
        xb[i] = f2bu(v);
    }
}

// ---------------- bilinear head via MFMA ----------------
__global__ __launch_bounds__(256) void k_q(const float* __restrict__ x, const int* __restrict__ cidx,
                                           const unsigned short* __restrict__ Bq, // 384x72 bf16
                                           const float* __restrict__ adjb,
                                           const float* __restrict__ fc1w,
                                           const float* __restrict__ fc1b,
                                           float* __restrict__ logp) {
    __shared__ __attribute__((aligned(16))) unsigned short Aq[64 * 72];  // 9216B
    __shared__ __attribute__((aligned(16))) unsigned short Bl[384 * 72]; // 55296B
    __shared__ float qv[64][6];
    int t = threadIdx.x;
    int p0 = blockIdx.x * 64;
    for (int i = t; i < 64 * 72; i += 256) {
        int a = i / 72, k = i - a * 72;
        int ga = p0 + a;
        float v = (k < 64 && ga < NATOM) ? x[(size_t)cidx[ga < NATOM ? ga : 0] * AA + k] : 0.f;
        Aq[i] = f2bu(v);
    }
    for (int i = t; i < 3456; i += 256)
        reinterpret_cast<uint4*>(Bl)[i] = reinterpret_cast<const uint4*>(Bq)[i];
    __syncthreads();

    int w = t >> 6, lane = t & 63, ln = lane & 15, quad = lane >> 4;
    f32x4 acc[24];
    f32x4 z4 = {0.f, 0.f, 0.f, 0.f};
    #pragma unroll
    for (int i = 0; i < 24; ++i) acc[i] = z4;
    {
        int mrow = w * 16 + ln;
        s16x8 a0 = *reinterpret_cast<const s16x8*>(&Aq[mrow * 72 + quad * 8]);
        s16x8 a1 = *reinterpret_cast<const s16x8*>(&Aq[mrow * 72 + quad * 8 + 32]);
        #pragma unroll
        for (int nt = 0; nt < 24; ++nt) {
            int nrow = nt * 16 + ln;
            s16x8 b0 = *reinterpret_cast<const s16x8*>(&Bl[nrow * 72 + quad * 8]);
            s16x8 b1 = *reinterpret_cast<const s16x8*>(&Bl[nrow * 72 + quad * 8 + 32]);
            acc[nt] = __builtin_amdgcn_mfma_f32_16x16x32_bf16(a0, b0, acc[nt], 0, 0, 0);
            acc[nt] = __builtin_amdgcn_mfma_f32_16x16x32_bf16(a1, b1, acc[nt], 0, 0, 0);
        }
    }
    float cfv[4][4];
    #pragma unroll
    for (int reg = 0; reg < 4; ++reg) {
        int ga = p0 + w * 16 + quad * 4 + reg;
        const float* xr = x + (size_t)cidx[ga < NATOM ? ga : 0] * AA;
        #pragma unroll
        for (int et = 0; et < 4; ++et)
            cfv[reg][et] = (ga < NATOM) ? xr[et * 16 + ln] : 0.f;
    }
    float bo[6];
    #pragma unroll
    for (int o = 0; o < 6; ++o) bo[o] = adjb[o];
    #pragma unroll
    for (int reg = 0; reg < 4; ++reg) {
        #pragma unroll
        for (int o = 0; o < 6; ++o) {
            float p = 0.f;
            #pragma unroll
            for (int et = 0; et < 4; ++et)
                p += acc[o * 4 + et][reg] * cfv[reg][et];
            p += __shfl_xor(p, 1); p += __shfl_xor(p, 2);
            p += __shfl_xor(p, 4); p += __shfl_xor(p, 8);
            if (ln == 0) qv[w * 16 + quad * 4 + reg][o] = p + bo[o];
        }
    }
    __syncthreads();
    if (t < 64) {
        int ga = p0 + t;
        if (ga < NATOM) {
            float q2[6];
            float mx = -1e30f;
            #pragma unroll
            for (int o2 = 0; o2 < 6; ++o2) {
                float acc2 = fc1b[o2];
                #pragma unroll
                for (int o = 0; o < 6; ++o) acc2 += qv[t][o] * fc1w[o * 6 + o2];
                q2[o2] = acc2; mx = fmaxf(mx, acc2);
            }
            float se = 0.f;
            #pragma unroll
            for (int o2 = 0; o2 < 6; ++o2) se += __expf(q2[o2] - mx);
            float lse = mx + __logf(se);
            #pragma unroll
            for (int o2 = 0; o2 < 6; ++o2) logp[(size_t)ga * 6 + o2] = q2[o2] - lse;
        }
    }
}

// ---------------- edge_prob broadcast write ----------------
__global__ void k_edge(const float* __restrict__ logp, float* __restrict__ out0) {
    int i4 = blockIdx.x * blockDim.x + threadIdx.x;
    if (i4 >= (NB * NPCC * NPCC * 6) / 4) return;
    int e = i4 * 4;
    int b = e / (NPCC * NPCC * 6);
    int rr = e - b * (NPCC * NPCC * 6);
    const float* lb = &logp[(size_t)b * NPCC * 6];
    float4 v;
    int r0 = rr % 300;       v.x = lb[r0];
    int r1 = (rr + 1) % 300; v.y = lb[r1];
    int r2 = (rr + 2) % 300; v.z = lb[r2];
    int r3 = (rr + 3) % 300; v.w = lb[r3];
    *reinterpret_cast<float4*>(&out0[e]) = v;
}

// ---------------- atom_feature = cf @ af_w + af_b (16 atoms/block) ----------------
__global__ __launch_bounds__(256) void k_af(const float* __restrict__ x, const int* __restrict__ cidx,
                                            const float* __restrict__ afw,
                                            const float* __restrict__ afb,
                                            float* __restrict__ out1) {
    __shared__ float wl[AA * ORIGD];   // 23552B
    __shared__ float cfl[16][AA];      // 4096B
    __shared__ float bl[ORIGD];
    int t = threadIdx.x;
    for (int i = t; i < AA * ORIGD; i += 256) wl[i] = afw[i];
    if (t < ORIGD) bl[t] = afb[t];
    int p0 = blockIdx.x * 16;
    for (int i = t; i < 16 * AA; i += 256) {
        int a = i >> 6, e = i & 63;
        cfl[a][e] = x[(size_t)cidx[p0 + a] * AA + e];
    }
    __syncthreads();
    for (int i = t; i < 16 * ORIGD; i += 256) {
        int a = i / ORIGD, c = i - a * ORIGD;
        float acc = bl[c];
        #pragma unroll 8
        for (int k = 0; k < AA; ++k)
            acc += cfl[a][k] * wl[k * ORIGD + c];
        out1[(size_t)(p0 + a) * ORIGD + c] = acc;
    }
}

extern "C" void kernel_launch(void* const* d_in, const int* in_sizes, int n_in,
                              void* d_out, int out_size, void* d_ws, size_t ws_size,
                              hipStream_t stream) {
    (void)in_sizes; (void)n_in; (void)out_size; (void)ws_size;
    const float* atom_fea  = (const float*)d_in[0];
    const float* nbr_fea   = (const float*)d_in[1];
    const int*   nbr_idx   = (const int*)d_in[2];
    const int*   cidx      = (const int*)d_in[3];
    const float* emb_w     = (const float*)d_in[4];
    const float* fc_full_w = (const float*)d_in[5];
    // d_in[6] fc_full_b: cancelled by batchnorm
    const float* bn1_g = (const float*)d_in[7];
    const float* bn1_b = (const float*)d_in[8];
    const float* bn2_g = (const float*)d_in[9];
    const float* bn2_b = (const float*)d_in[10];
    const float* adj_w = (const float*)d_in[11];
    const float* adj_b = (const float*)d_in[12];
    const float* fc1_w = (const float*)d_in[13];
    const float* fc1_b = (const float*)d_in[14];
    const float* af_w  = (const float*)d_in[15];
    const float* af_b  = (const float*)d_in[16];

    float* out0 = (float*)d_out;
    float* out1 = out0 + (size_t)NB * NPCC * NPCC * 6;

    float* ws = (float*)d_ws;
    float* x      = ws;
    float* summed = x + (size_t)NATOM * AA;
    float* logp   = summed + (size_t)NATOM * AA;
    float* stats1 = logp + (size_t)NATOM * 6;          // [NREP][256]
    float* stats2 = stats1 + (size_t)NREP * 256;       // [NREP][128]
    float* sc1    = stats2 + (size_t)NREP * 128;       // [256]
    float* sc2    = sc1 + 256;                         // [128]
    float* endf   = sc2 + 128;
    size_t off = (((size_t)((char*)endf - (char*)d_ws)) + 255) & ~(size_t)255;
    unsigned short* xb = (unsigned short*)((char*)d_ws + off);   // NATOM*64 bf16 (6.4MB)
    unsigned short* Wt = xb + (size_t)NATOM * 64;                // 3*128*72 bf16
    unsigned short* Bq = Wt + 3 * 9216;                          // 384*72 bf16
    size_t goff = (off + ((size_t)NATOM * 64 + 3 * 9216 + 384 * 72) * 2 + 255) & ~(size_t)255;
    uint4* gated = (uint4*)((char*)d_ws + goff);                 // 3125*3072 uint4 = 153.6MB

    const int nstat = NREP * 256 + NREP * 128; // 24576 floats
    k_embed<<<NATOM / 4, 256, 0, stream>>>(atom_fea, emb_w, x, xb);
    k_prepQ<<<108, 256, 0, stream>>>(adj_w, Bq);
    for (int layer = 0; layer < 3; ++layer) {
        const float* W = fc_full_w + (size_t)layer * 169 * 128;
        k_prep0<<<15, 256, 0, stream>>>(W, Wt, stats1, nstat);
        k_passA<<<NATOM / 16, 256, 0, stream>>>(xb, nbr_fea, Wt, nbr_idx, stats1, gated);
        k_sc1<<<1, 128, 0, stream>>>(stats1, bn1_g + layer * 128, bn1_b + layer * 128, sc1);
        k_passBs<<<NATOM / 16, 256, 0, stream>>>(gated, sc1, summed, stats2);
        k_sc2<<<1, 64, 0, stream>>>(stats2, bn2_g + layer * 64, bn2_b + layer * 64, sc2);
        k_update<<<(NATOM * AA + 255) / 256, 256, 0, stream>>>(x, summed, sc2, xb);
    }
    k_q<<<(NATOM + 63) / 64, 256, 0, stream>>>(x, cidx, Bq, adj_b, fc1_w, fc1_b, logp);
    k_edge<<<((NB * NPCC * NPCC * 6) / 4 + 255) / 256, 256, 0, stream>>>(logp, out0);
    k_af<<<NATOM / 16, 256, 0, stream>>>(x, cidx, af_w, af_b, out1);
}

// Round 10
// 708.278 us; speedup vs baseline: 1.8571x; 1.0730x over previous
//
#include <hip/hip_runtime.h>
#include <hip/hip_bf16.h>

#define AA 64
#define NBRF 41
#define ORIGD 92
#define NATOM 50000
#define MM 12
#define NB 1000
#define NPCC 50
#define NEDGE (NATOM*MM)
#define NREP 64
constexpr float EPS_BN = 1e-5f;

using bf16 = __hip_bfloat16;
typedef short s16x8 __attribute__((ext_vector_type(8)));
typedef float f32x4 __attribute__((ext_vector_type(4)));

__device__ __forceinline__ float u2f(unsigned short u) {
    union { float f; unsigned int i; } v; v.i = ((unsigned int)u) << 16; return v.f;
}
__device__ __forceinline__ unsigned short f2bu(float f) {
    bf16 h = __float2bfloat16(f);
    return *reinterpret_cast<unsigned short*>(&h);
}
__device__ __forceinline__ float fsigmoid(float x) {
    float e = __expf(-x);
    return __builtin_amdgcn_rcpf(1.f + e);
}
__device__ __forceinline__ float fsoftplus(float x) {
    return fmaxf(x, 0.f) + __logf(1.f + __expf(-fabsf(x)));
}

// global->LDS direct DMA, 16B per lane, lane l lands at lds + l*16.
// NOTE: the GLOBAL source address is PER-LANE — caller must include the
// lane offset in g (R5 bug: uniform source = 64 copies of the same 16B).
#define GLD16(g, l)                                                              \
    __builtin_amdgcn_global_load_lds(                                            \
        (const __attribute__((address_space(1))) unsigned int*)(g),              \
        (__attribute__((address_space(3))) unsigned int*)(l), 16, 0, 0)

// ---------------- one-time: nbr_fea f32 [NEDGE][41] -> nbp bf16 [NEDGE][48] ----------------
// Cols 41..47 zeroed. Cols >=41 of W2t are zero, so phase-1 A-fragment reads past
// col 47 contribute A*0 — but A MUST be finite (0*NaN=NaN; R8 bug: row 191's
// overrun read uninitialized LDS -> NaN). k_passA zeroes the LDS tail region.
__global__ __launch_bounds__(256) void k_prepN(const float* __restrict__ nf,
                                               unsigned short* __restrict__ nbp) {
    const int total = NEDGE * 6; // 16B chunks (48 cols / 8)
    for (int i = blockIdx.x * 256 + threadIdx.x; i < total; i += gridDim.x * 256) {
        int row = i / 6, j = i - row * 6;
        const float* src = nf + (size_t)row * NBRF + j * 8;
        int base = j * 8;
        unsigned short h[8];
        #pragma unroll
        for (int e = 0; e < 8; ++e)
            h[e] = (base + e < NBRF) ? f2bu(src[e]) : (unsigned short)0;
        uint4 u;
        u.x = (unsigned)h[0] | ((unsigned)h[1] << 16);
        u.y = (unsigned)h[2] | ((unsigned)h[3] << 16);
        u.z = (unsigned)h[4] | ((unsigned)h[5] << 16);
        u.w = (unsigned)h[6] | ((unsigned)h[7] << 16);
        *reinterpret_cast<uint4*>(nbp + (size_t)row * 48 + j * 8) = u;
    }
}

// ---------------- merged: prep Wt (3 transposed bf16 W parts) + zero stats ----------------
// Wt layout: part p in [0,3): [128 rows(n)][72 cols(k)] bf16.
//   p=0: W2t (nbr_fea weights, k<41), p=1: W1t (x_nbr, k<64), p=2: W0t (x_self, k<64)
__global__ void k_prep0(const float* __restrict__ W, unsigned short* __restrict__ Wt,
                        float* __restrict__ stats, int nstat) {
    int b = blockIdx.x, t = threadIdx.x;
    if (b < 3) {
        for (int i = t; i < 9216; i += 256) {
            int n = i / 72, k = i - n * 72;
            float v = 0.f;
            if (b == 0)      { if (k < NBRF) v = W[(128 + k) * 128 + n]; }
            else if (b == 1) { if (k < 64)   v = W[(64 + k) * 128 + n]; }
            else             { if (k < 64)   v = W[k * 128 + n]; }
            Wt[b * 9216 + i] = f2bu(v);
        }
    } else {
        int base = (b - 3) * 2048;
        for (int i = t; i < 2048; i += 256) {
            int idx = base + i;
            if (idx < nstat) stats[idx] = 0.f;
        }
    }
}

// ---------------- prep: adj_w -> Bq bf16 [384 rows(n=o*64+e)][72 (k=d, padded)] ----------------
__global__ void k_prepQ(const float* __restrict__ adjw, unsigned short* __restrict__ Bq) {
    int i = blockIdx.x * 256 + threadIdx.x; // 384*72 = 27648
    if (i >= 384 * 72) return;
    int n = i / 72, k = i - n * 72;
    float v = (k < 64) ? adjw[(n >> 6) * 4096 + k * 64 + (n & 63)] : 0.f;
    Bq[i] = f2bu(v);
}

// ---------------- embed: xb = bf16(atom_fea @ emb_w)  (N,92)@(92,64) ----------------
__global__ __launch_bounds__(256) void k_embed(const float* __restrict__ af,
                                               const float* __restrict__ w,
                                               unsigned short* __restrict__ xb) {
    __shared__ float wl[ORIGD * AA];
    __shared__ float al[4][ORIGD];
    int t = threadIdx.x;
    for (int i = t; i < ORIGD * AA; i += 256) wl[i] = w[i];
    int n0 = blockIdx.x * 4;
    for (int i = t; i < 4 * ORIGD; i += 256) {
        int a = i / ORIGD, k = i - a * ORIGD;
        al[a][k] = af[(size_t)(n0 + a) * ORIGD + k];
    }
    __syncthreads();
    int c = t & 63, a = t >> 6;
    float acc = 0.f;
    #pragma unroll 4
    for (int k = 0; k < ORIGD; ++k)
        acc += al[a][k] * wl[k * AA + c];
    xb[(size_t)(n0 + a) * AA + c] = f2bu(acc);
}

// ================= fused MFMA edge-GEMM pass A (v7c) =================
// Per block: 16 atoms -> 192 edges.
// gated = nbr@W2 + x_nbr@W1 + x_self@W0 via 3 accumulating bf16 MFMA phases.
// ALL staging via global_load_lds: nbp (pre-converted bf16, 48-col), x gathers,
// W double-buffered (Bl0=W2t, Bl1=W1t upfront; W0t + x-gathers at single mid
// sync). A region: phase1 holds [192][48] nbp; phase2 holds [192][64] gathered x.
// Phases 2->3 barrier-free. 4 barriers total before epilogue.

__global__ __launch_bounds__(256, 2) void k_passA(const unsigned short* __restrict__ xb,
                                                  const unsigned short* __restrict__ nbp,
                                                  const unsigned short* __restrict__ Wt,
                                                  const int* __restrict__ nidx,
                                                  float* __restrict__ stats,
                                                  uint4* __restrict__ gated) {
    // A 192*64 (24576B) | As 16*64 (2048B) | Bl0 128*72 (18432B) | Bl1 128*72 (18432B) = 63488B
    __shared__ __attribute__((aligned(16))) unsigned char SMEM[63488];
    unsigned short* A   = reinterpret_cast<unsigned short*>(SMEM);
    unsigned short* As  = A + 192 * 64;
    unsigned short* Bl0 = As + 16 * 64;
    unsigned short* Bl1 = Bl0 + 128 * 72;
    int t = threadIdx.x;
    int n0 = blockIdx.x * 16;
    int w = t >> 6, lane = t & 63, ln = lane & 15, quad = lane >> 4;

    // ---- upfront DMA: A <- nbp block rows ([192][48], 18 chunks), Bl0 <- W2t,
    //      Bl1 <- W1t, As <- x_self (swizzled source) ----
    const unsigned short* nbrow = nbp + (size_t)n0 * MM * 48;
    for (int c = w; c < 18; c += 4)
        GLD16(nbrow + c * 512 + lane * 8, (char*)A + c * 1024);
    for (int c = w; c < 18; c += 4)
        GLD16(Wt + c * 512 + lane * 8, (char*)Bl0 + c * 1024);
    for (int c = w; c < 18; c += 4)
        GLD16(Wt + 9216 + c * 512 + lane * 8, (char*)Bl1 + c * 1024);
    int sl = ((lane & 7) ^ ((lane >> 3) & 7)) * 8;  // pre-swizzled source slot
    if (w == 3) {
        GLD16(xb + (size_t)(n0 + (lane >> 3)) * 64 + sl, (char*)As);
        GLD16(xb + (size_t)(n0 + 8 + (lane >> 3)) * 64 + sl, (char*)As + 1024);
    }
    // R8 NaN fix: zero the LDS tail past the 192x48 staged region. Row 191's
    // phase-1 fragment reads A[9216..9232); uninit LDS there can be NaN-pattern
    // bf16, and 0*NaN = NaN. Zero [9216..9280) for margin (ds_write disjoint
    // from DMA destinations, ordered by the barrier below).
    if (t < 64) A[192 * 48 + t] = 0;
    // neighbor indices for this wave's x-gather rows (VGPR, 8-lane broadcast)
    const int* nb = nidx + n0 * MM;
    int idxv[6];
    #pragma unroll
    for (int c = 0; c < 6; ++c) idxv[c] = nb[w * 48 + c * 8 + (lane >> 3)];
    __syncthreads(); // drains all upfront DMA

    f32x4 acc[3][8];
    f32x4 z4 = {0.f, 0.f, 0.f, 0.f};
    for (int i = 0; i < 3; ++i) for (int j = 0; j < 8; ++j) acc[i][j] = z4;
    int sw0 = (quad ^ (ln & 7)) * 8, sw1 = ((quad + 4) ^ (ln & 7)) * 8;

    // ---- phase 1: nbr @ W2 (A = [192][48] nbp; cols>=41 of B are zero) ----
    #pragma unroll
    for (int mt = 0; mt < 3; ++mt) {
        int mrow = w * 48 + mt * 16 + ln;
        s16x8 a0 = *reinterpret_cast<const s16x8*>(&A[mrow * 48 + quad * 8]);
        s16x8 a1 = *reinterpret_cast<const s16x8*>(&A[mrow * 48 + quad * 8 + 32]);
        #pragma unroll
        for (int nt = 0; nt < 8; ++nt) {
            int nrow = nt * 16 + ln;
            s16x8 b0 = *reinterpret_cast<const s16x8*>(&Bl0[nrow * 72 + quad * 8]);
            s16x8 b1 = *reinterpret_cast<const s16x8*>(&Bl0[nrow * 72 + quad * 8 + 32]);
            acc[mt][nt] = __builtin_amdgcn_mfma_f32_16x16x32_bf16(a0, b0, acc[mt][nt], 0, 0, 0);
            acc[mt][nt] = __builtin_amdgcn_mfma_f32_16x16x32_bf16(a1, b1, acc[mt][nt], 0, 0, 0);
        }
    }
    __syncthreads(); // A + Bl0 readers done
    // ---- issue x-gathers into A ([192][64] swizzled) and W0t into Bl0 ----
    #pragma unroll
    for (int c = 0; c < 6; ++c)
        GLD16(xb + (size_t)idxv[c] * 64 + sl, (char*)A + (w * 48 + c * 8) * 128);
    for (int c = w; c < 18; c += 4)
        GLD16(Wt + 2 * 9216 + c * 512 + lane * 8, (char*)Bl0 + c * 1024);
    __syncthreads(); // drains

    // ---- phase 2: x_nbr @ W1 (A = gathered x, swizzled read; Bl1) ----
    #pragma unroll
    for (int mt = 0; mt < 3; ++mt) {
        int mrow = w * 48 + mt * 16 + ln;
        s16x8 a0 = *reinterpret_cast<const s16x8*>(&A[mrow * 64 + sw0]);
        s16x8 a1 = *reinterpret_cast<const s16x8*>(&A[mrow * 64 + sw1]);
        #pragma unroll
        for (int nt = 0; nt < 8; ++nt) {
            int nrow = nt * 16 + ln;
            s16x8 b0 = *reinterpret_cast<const s16x8*>(&Bl1[nrow * 72 + quad * 8]);
            s16x8 b1 = *reinterpret_cast<const s16x8*>(&Bl1[nrow * 72 + quad * 8 + 32]);
            acc[mt][nt] = __builtin_amdgcn_mfma_f32_16x16x32_bf16(a0, b0, acc[mt][nt], 0, 0, 0);
            acc[mt][nt] = __builtin_amdgcn_mfma_f32_16x16x32_bf16(a1, b1, acc[mt][nt], 0, 0, 0);
        }
    }
    // ---- phase 3: x_self @ W0 (As, Bl0) — no barrier needed ----
    #pragma unroll
    for (int mt = 0; mt < 3; ++mt) {
        int mrow = w * 48 + mt * 16 + ln;
        int atom = mrow / 12;
        int s0 = (quad ^ (atom & 7)) * 8, s1 = ((quad + 4) ^ (atom & 7)) * 8;
        s16x8 a0 = *reinterpret_cast<const s16x8*>(&As[atom * 64 + s0]);
        s16x8 a1 = *reinterpret_cast<const s16x8*>(&As[atom * 64 + s1]);
        #pragma unroll
        for (int nt = 0; nt < 8; ++nt) {
            int nrow = nt * 16 + ln;
            s16x8 b0 = *reinterpret_cast<const s16x8*>(&Bl0[nrow * 72 + quad * 8]);
            s16x8 b1 = *reinterpret_cast<const s16x8*>(&Bl0[nrow * 72 + quad * 8 + 32]);
            acc[mt][nt] = __builtin_amdgcn_mfma_f32_16x16x32_bf16(a0, b0, acc[mt][nt], 0, 0, 0);
            acc[mt][nt] = __builtin_amdgcn_mfma_f32_16x16x32_bf16(a1, b1, acc[mt][nt], 0, 0, 0);
        }
    }

    // ---- epilogue: BN1 stats + bf16 pack + coalesced store ----
    uint4* gblk = gated + (size_t)blockIdx.x * 3072;
    float s[8] = {0,0,0,0,0,0,0,0}, q[8] = {0,0,0,0,0,0,0,0};
    #pragma unroll
    for (int mt = 0; mt < 3; ++mt) {
        #pragma unroll
        for (int reg = 0; reg < 4; ++reg) {
            float r[8];
            #pragma unroll
            for (int nt = 0; nt < 8; ++nt) {
                r[nt] = acc[mt][nt][reg];
                s[nt] += r[nt]; q[nt] += r[nt] * r[nt];
            }
            uint4 u;
            u.x = (unsigned)f2bu(r[0]) | ((unsigned)f2bu(r[1]) << 16);
            u.y = (unsigned)f2bu(r[2]) | ((unsigned)f2bu(r[3]) << 16);
            u.z = (unsigned)f2bu(r[4]) | ((unsigned)f2bu(r[5]) << 16);
            u.w = (unsigned)f2bu(r[6]) | ((unsigned)f2bu(r[7]) << 16);
            gblk[(mt * 4 + reg) * 256 + t] = u; // coalesced per (mt,reg)
        }
    }
    #pragma unroll
    for (int nt = 0; nt < 8; ++nt) {
        s[nt] += __shfl_xor(s[nt], 16); s[nt] += __shfl_xor(s[nt], 32);
        q[nt] += __shfl_xor(q[nt], 16); q[nt] += __shfl_xor(q[nt], 32);
    }
    __syncthreads(); // staging regions dead -> alias as red
    float* red = reinterpret_cast<float*>(SMEM); // [4 waves][8 nt][16 ln][2]
    if (quad == 0) {
        #pragma unroll
        for (int nt = 0; nt < 8; ++nt) {
            red[((w * 8 + nt) * 16 + ln) * 2 + 0] = s[nt];
            red[((w * 8 + nt) * 16 + ln) * 2 + 1] = q[nt];
        }
    }
    __syncthreads();
    {
        int c = t >> 1, j = t & 1; // c in 0..127
        float v = 0.f;
        #pragma unroll
        for (int w2 = 0; w2 < 4; ++w2)
            v += red[((w2 * 8 + (c >> 4)) * 16 + (c & 15)) * 2 + j];
        int rep = (blockIdx.x & (NREP - 1)) << 8;
        atomicAdd(&stats[rep + j * 128 + c], v);
    }
}

// ---------------- bn1 fold (sums NREP replicas) ----------------
__global__ void k_sc1(const float* __restrict__ stats, const float* __restrict__ g,
                      const float* __restrict__ b, float* __restrict__ sc) {
    int c = threadIdx.x; // 128
    float s = 0.f, q = 0.f;
    for (int r = 0; r < NREP; ++r) {
        s += stats[r * 256 + c];
        q += stats[r * 256 + 128 + c];
    }
    float cnt = (float)NEDGE;
    float mean = s / cnt;
    float var = q / cnt - mean * mean;
    float inv = rsqrtf(var + EPS_BN);
    float scale = g[c] * inv;
    sc[c] = scale;
    sc[128 + c] = b[c] - mean * scale;
}

// ---------------- pass B (streaming): read gated, BN1+act, sum over neighbors ----------------
__global__ __launch_bounds__(256) void k_passBs(const uint4* __restrict__ gated,
                                                const float* __restrict__ sc,
                                                float* __restrict__ summed,
                                                float* __restrict__ stats2) {
    __shared__ unsigned short P[192 * 66]; // 25344B
    __shared__ float sred[512];
    int t = threadIdx.x;
    int n0 = blockIdx.x * 16;
    int w = t >> 6, lane = t & 63, ln = lane & 15, quad = lane >> 4;
    float scF[4], shF[4], scC[4], shC[4];
    #pragma unroll
    for (int nt = 0; nt < 4; ++nt) {
        int cc = nt * 16 + ln;
        scF[nt] = sc[cc];      shF[nt] = sc[128 + cc];
        scC[nt] = sc[64 + cc]; shC[nt] = sc[192 + cc];
    }
    const uint4* gblk = gated + (size_t)blockIdx.x * 3072;
    #pragma unroll
    for (int mt = 0; mt < 3; ++mt) {
        #pragma unroll
        for (int reg = 0; reg < 4; ++reg) {
            uint4 u = gblk[(mt * 4 + reg) * 256 + t];
            int m = (w * 3 + mt) * 16 + quad * 4 + reg;
            unsigned uu[4] = {u.x, u.y, u.z, u.w};
            #pragma unroll
            for (int nt = 0; nt < 4; ++nt) {
                float rfv = u2f((unsigned short)((nt & 1) ? (uu[nt >> 1] >> 16) : (uu[nt >> 1] & 0xffff)));
                float rcv = u2f((unsigned short)((nt & 1) ? (uu[2 + (nt >> 1)] >> 16) : (uu[2 + (nt >> 1)] & 0xffff)));
                float rf = rfv * scF[nt] + shF[nt];
                float rc = rcv * scC[nt] + shC[nt];
                P[m * 66 + nt * 16 + ln] = f2bu(fsigmoid(rf) * fsoftplus(rc));
            }
        }
    }
    __syncthreads();
    int cc = t & 63, who = t >> 6;
    float sA = 0.f, qA = 0.f;
    #pragma unroll
    for (int k2 = 0; k2 < 4; ++k2) {
        int a = who + k2 * 4;
        float v = 0.f;
        #pragma unroll
        for (int j = 0; j < 12; ++j) v += u2f(P[(a * 12 + j) * 66 + cc]);
        summed[(size_t)(n0 + a) * AA + cc] = v;
        sA += v; qA += v * v;
    }
    sred[who * 64 + cc] = sA;
    sred[256 + who * 64 + cc] = qA;
    __syncthreads();
    if (t < 64) {
        float s4 = sred[t] + sred[64 + t] + sred[128 + t] + sred[192 + t];
        float q4 = sred[256 + t] + sred[320 + t] + sred[384 + t] + sred[448 + t];
        int rep = (blockIdx.x & (NREP - 1)) << 7; // replicas of [128]
        atomicAdd(&stats2[rep + t], s4);
        atomicAdd(&stats2[rep + 64 + t], q4);
    }
}

// ---------------- bn2 fold (sums NREP replicas) ----------------
__global__ void k_sc2(const float* __restrict__ stats2, const float* __restrict__ g,
                      const float* __restrict__ b, float* __restrict__ sc2) {
    int c = threadIdx.x; // 64
    float s = 0.f, q = 0.f;
    for (int r = 0; r < NREP; ++r) {
        s += stats2[r * 128 + c];
        q += stats2[r * 128 + 64 + c];
    }
    float cnt = (float)NATOM;
    float mean = s / cnt;
    float var = q / cnt - mean * mean;
    float inv = rsqrtf(var + EPS_BN);
    float scale = g[c] * inv;
    sc2[c] = scale;
    sc2[64 + c] = b[c] - mean * scale;
}

// ---------------- xb = bf16(softplus(xb + bn2(summed))) ----------------
__global__ void k_update(unsigned short* __restrict__ xb, const float* __restrict__ summed,
                         const float* __restrict__ sc2) {
    int i = blockIdx.x * blockDim.x + threadIdx.x;
    if (i < NATOM * AA) {
        int c = i & 63;
        float s = summed[i] * sc2[c] + sc2[64 + c];
        xb[i] = f2bu(fsoftplus(u2f(xb[i]) + s));
    }
}

// ---------------- bilinear head via MFMA (reads xb) ----------------
__global__ __launch_bounds__(256) void k_q(const unsigned short* __restrict__ xb,
                                           const int* __restrict__ cidx,
                                           const unsigned short* __restrict__ Bq, // 384x72 bf16
                                           const float* __restrict__ adjb,
                                           const float* __restrict__ fc1w,
                                           const float* __restrict__ fc1b,
                                           float* __restrict__ logp) {
    __shared__ __attribute__((aligned(16))) unsigned short Aq[64 * 72];  // 9216B
    __shared__ __attribute__((aligned(16))) unsigned short Bl[384 * 72]; // 55296B
    __shared__ float qv[64][6];
    int t = threadIdx.x;
    int p0 = blockIdx.x * 64;
    for (int i = t; i < 64 * 72; i += 256) {
        int a = i / 72, k = i - a * 72;
        int ga = p0 + a;
        Aq[i] = (k < 64 && ga < NATOM)
            ? xb[(size_t)cidx[ga < NATOM ? ga : 0] * AA + k] : (unsigned short)0;
    }
    for (int i = t; i < 3456; i += 256)
        reinterpret_cast<uint4*>(Bl)[i] = reinterpret_cast<const uint4*>(Bq)[i];
    __syncthreads();

    int w = t >> 6, lane = t & 63, ln = lane & 15, quad = lane >> 4;
    f32x4 acc[24];
    f32x4 z4 = {0.f, 0.f, 0.f, 0.f};
    #pragma unroll
    for (int i = 0; i < 24; ++i) acc[i] = z4;
    {
        int mrow = w * 16 + ln;
        s16x8 a0 = *reinterpret_cast<const s16x8*>(&Aq[mrow * 72 + quad * 8]);
        s16x8 a1 = *reinterpret_cast<const s16x8*>(&Aq[mrow * 72 + quad * 8 + 32]);
        #pragma unroll
        for (int nt = 0; nt < 24; ++nt) {
            int nrow = nt * 16 + ln;
            s16x8 b0 = *reinterpret_cast<const s16x8*>(&Bl[nrow * 72 + quad * 8]);
            s16x8 b1 = *reinterpret_cast<const s16x8*>(&Bl[nrow * 72 + quad * 8 + 32]);
            acc[nt] = __builtin_amdgcn_mfma_f32_16x16x32_bf16(a0, b0, acc[nt], 0, 0, 0);
            acc[nt] = __builtin_amdgcn_mfma_f32_16x16x32_bf16(a1, b1, acc[nt], 0, 0, 0);
        }
    }
    float cfv[4][4];
    #pragma unroll
    for (int reg = 0; reg < 4; ++reg) {
        int ga = p0 + w * 16 + quad * 4 + reg;
        const unsigned short* xr = xb + (size_t)cidx[ga < NATOM ? ga : 0] * AA;
        #pragma unroll
        for (int et = 0; et < 4; ++et)
            cfv[reg][et] = (ga < NATOM) ? u2f(xr[et * 16 + ln]) : 0.f;
    }
    float bo[6];
    #pragma unroll
    for (int o = 0; o < 6; ++o) bo[o] = adjb[o];
    #pragma unroll
    for (int reg = 0; reg < 4; ++reg) {
        #pragma unroll
        for (int o = 0; o < 6; ++o) {
            float p = 0.f;
            #pragma unroll
            for (int et = 0; et < 4; ++et)
                p += acc[o * 4 + et][reg] * cfv[reg][et];
            p += __shfl_xor(p, 1); p += __shfl_xor(p, 2);
            p += __shfl_xor(p, 4); p += __shfl_xor(p, 8);
            if (ln == 0) qv[w * 16 + quad * 4 + reg][o] = p + bo[o];
        }
    }
    __syncthreads();
    if (t < 64) {
        int ga = p0 + t;
        if (ga < NATOM) {
            float q2[6];
            float mx = -1e30f;
            #pragma unroll
            for (int o2 = 0; o2 < 6; ++o2) {
                float acc2 = fc1b[o2];
                #pragma unroll
                for (int o = 0; o < 6; ++o) acc2 += qv[t][o] * fc1w[o * 6 + o2];
                q2[o2] = acc2; mx = fmaxf(mx, acc2);
            }
            float se = 0.f;
            #pragma unroll
            for (int o2 = 0; o2 < 6; ++o2) se += __expf(q2[o2] - mx);
            float lse = mx + __logf(se);
            #pragma unroll
            for (int o2 = 0; o2 < 6; ++o2) logp[(size_t)ga * 6 + o2] = q2[o2] - lse;
        }
    }
}

// ---------------- edge_prob broadcast write ----------------
__global__ void k_edge(const float* __restrict__ logp, float* __restrict__ out0) {
    int i4 = blockIdx.x * blockDim.x + threadIdx.x;
    if (i4 >= (NB * NPCC * NPCC * 6) / 4) return;
    int e = i4 * 4;
    int b = e / (NPCC * NPCC * 6);
    int rr = e - b * (NPCC * NPCC * 6);
    const float* lb = &logp[(size_t)b * NPCC * 6];
    float4 v;
    int r0 = rr % 300;       v.x = lb[r0];
    int r1 = (rr + 1) % 300; v.y = lb[r1];
    int r2 = (rr + 2) % 300; v.z = lb[r2];
    int r3 = (rr + 3) % 300; v.w = lb[r3];
    *reinterpret_cast<float4*>(&out0[e]) = v;
}

// ---------------- atom_feature = cf @ af_w + af_b (16 atoms/block, reads xb) ----------------
__global__ __launch_bounds__(256) void k_af(const unsigned short* __restrict__ xb,
                                            const int* __restrict__ cidx,
                                            const float* __restrict__ afw,
                                            const float* __restrict__ afb,
                                            float* __restrict__ out1) {
    __shared__ float wl[AA * ORIGD];   // 23552B
    __shared__ float cfl[16][AA];      // 4096B
    __shared__ float bl[ORIGD];
    int t = threadIdx.x;
    for (int i = t; i < AA * ORIGD; i += 256) wl[i] = afw[i];
    if (t < ORIGD) bl[t] = afb[t];
    int p0 = blockIdx.x * 16;
    for (int i = t; i < 16 * AA; i += 256) {
        int a = i >> 6, e = i & 63;
        cfl[a][e] = u2f(xb[(size_t)cidx[p0 + a] * AA + e]);
    }
    __syncthreads();
    for (int i = t; i < 16 * ORIGD; i += 256) {
        int a = i / ORIGD, c = i - a * ORIGD;
        float acc = bl[c];
        #pragma unroll 8
        for (int k = 0; k < AA; ++k)
            acc += cfl[a][k] * wl[k * ORIGD + c];
        out1[(size_t)(p0 + a) * ORIGD + c] = acc;
    }
}

extern "C" void kernel_launch(void* const* d_in, const int* in_sizes, int n_in,
                              void* d_out, int out_size, void* d_ws, size_t ws_size,
                              hipStream_t stream) {
    (void)in_sizes; (void)n_in; (void)out_size; (void)ws_size;
    const float* atom_fea  = (const float*)d_in[0];
    const float* nbr_fea   = (const float*)d_in[1];
    const int*   nbr_idx   = (const int*)d_in[2];
    const int*   cidx      = (const int*)d_in[3];
    const float* emb_w     = (const float*)d_in[4];
    const float* fc_full_w = (const float*)d_in[5];
    // d_in[6] fc_full_b: cancelled by batchnorm
    const float* bn1_g = (const float*)d_in[7];
    const float* bn1_b = (const float*)d_in[8];
    const float* bn2_g = (const float*)d_in[9];
    const float* bn2_b = (const float*)d_in[10];
    const float* adj_w = (const float*)d_in[11];
    const float* adj_b = (const float*)d_in[12];
    const float* fc1_w = (const float*)d_in[13];
    const float* fc1_b = (const float*)d_in[14];
    const float* af_w  = (const float*)d_in[15];
    const float* af_b  = (const float*)d_in[16];

    float* out0 = (float*)d_out;
    float* out1 = out0 + (size_t)NB * NPCC * NPCC * 6;

    // ---- workspace layout (231.8 MB total — within proven budget) ----
    float* ws = (float*)d_ws;
    float* summed = ws;                                // 12.8MB
    float* logp   = summed + (size_t)NATOM * AA;       // 1.2MB
    float* stats1 = logp + (size_t)NATOM * 6;          // [NREP][256]
    float* stats2 = stats1 + (size_t)NREP * 256;       // [NREP][128]
    float* sc1    = stats2 + (size_t)NREP * 128;       // [256]
    float* sc2    = sc1 + 256;                         // [128]
    float* endf   = sc2 + 128;
    size_t off = (((size_t)((char*)endf - (char*)d_ws)) + 255) & ~(size_t)255;
    unsigned short* xb  = (unsigned short*)((char*)d_ws + off);  // NATOM*64 bf16 (6.4MB)
    unsigned short* Wt  = xb + (size_t)NATOM * 64;               // 3*128*72 bf16
    unsigned short* Bq  = Wt + 3 * 9216;                         // 384*72 bf16
    unsigned short* nbp = Bq + 384 * 72;                         // NEDGE*48 bf16 (57.6MB)
    size_t goff = (off + ((size_t)NATOM * 64 + 3 * 9216 + 384 * 72 + (size_t)NEDGE * 48) * 2 + 255) & ~(size_t)255;
    uint4* gated = (uint4*)((char*)d_ws + goff);                 // 3125*3072 uint4 = 153.6MB

    const int nstat = NREP * 256 + NREP * 128; // 24576 floats
    k_prepN<<<2048, 256, 0, stream>>>(nbr_fea, nbp);
    k_embed<<<NATOM / 4, 256, 0, stream>>>(atom_fea, emb_w, xb);
    k_prepQ<<<108, 256, 0, stream>>>(adj_w, Bq);
    for (int layer = 0; layer < 3; ++layer) {
        const float* W = fc_full_w + (size_t)layer * 169 * 128;
        k_prep0<<<15, 256, 0, stream>>>(W, Wt, stats1, nstat);
        k_passA<<<NATOM / 16, 256, 0, stream>>>(xb, nbp, Wt, nbr_idx, stats1, gated);
        k_sc1<<<1, 128, 0, stream>>>(stats1, bn1_g + layer * 128, bn1_b + layer * 128, sc1);
        k_passBs<<<NATOM / 16, 256, 0, stream>>>(gated, sc1, summed, stats2);
        k_sc2<<<1, 64, 0, stream>>>(stats2, bn2_g + layer * 64, bn2_b + layer * 64, sc2);
        k_update<<<(NATOM * AA + 255) / 256, 256, 0, stream>>>(xb, summed, sc2);
    }
    k_q<<<(NATOM + 63) / 64, 256, 0, stream>>>(xb, cidx, Bq, adj_b, fc1_w, fc1_b, logp);
    k_edge<<<((NB * NPCC * NPCC * 6) / 4 + 255) / 256, 256, 0, stream>>>(logp, out0);
    k_af<<<NATOM / 16, 256, 0, stream>>>(xb, cidx, af_w, af_b, out1);
}